// Round 14
// baseline (1571.332 us; speedup 1.0000x reference)
//
#include <hip/hip_runtime.h>

#define HDIM 256
#define KA 107
#define KAP 128

typedef short bf16x8 __attribute__((ext_vector_type(8)));
typedef float f32x4 __attribute__((ext_vector_type(4)));
typedef unsigned short ushort_t;

__device__ inline unsigned short f2bf(float f) {
    union { float f; unsigned u; } v; v.f = f;
    unsigned r = v.u + 0x7fff + ((v.u >> 16) & 1);
    return (unsigned short)(r >> 16);
}

__device__ inline unsigned cvt_pk_bf16(float a, float b) {
    unsigned r;
    asm("v_cvt_pk_bf16_f32 %0, %1, %2" : "=v"(r) : "v"(a), "v"(b));
    return r;   // low16 = bf16(a), high16 = bf16(b)
}

__device__ inline float bf_lo(unsigned u) { union { unsigned v; float f; } x; x.v = u << 16; return x.f; }
__device__ inline float bf_hi(unsigned u) { union { unsigned v; float f; } x; x.v = u & 0xffff0000u; return x.f; }

__device__ inline float4 guarded_load4(const float* p, size_t off, size_t tot) {
    if (off + 4 <= tot) return *(const float4*)(p + off);
    float4 r = {0.f, 0.f, 0.f, 0.f};
    float* rr = (float*)&r;
    for (int e = 0; e < 4; ++e) if (off + e < tot) rr[e] = p[off + e];
    return r;
}

// ---------------- small kernels ----------------

// count histogram only (1 atomic per edge)
__global__ void hist_cnt_kernel(const int* __restrict__ dst, int* cnt, int ne) {
    int e = blockIdx.x * 256 + threadIdx.x;
    if (e < ne) atomicAdd(&cnt[dst[e]], 1);
}

// f32 -> bf16 mirror (float4 -> uint2)
__global__ void f32_to_bf16_kernel(const float* __restrict__ in, ushort_t* __restrict__ out, int n4) {
    int i = blockIdx.x * 256 + threadIdx.x;
    if (i < n4) {
        float4 v = ((const float4*)in)[i];
        uint2 o;
        o.x = cvt_pk_bf16(v.x, v.y);
        o.y = cvt_pk_bf16(v.z, v.w);
        ((uint2*)out)[i] = o;
    }
}

// ---------------- multi-block scan (3 phases) ----------------
// phase A: per-block sum of cnt[256] -> bsum[bid]
__global__ __launch_bounds__(256) void scan_a_kernel(const int* __restrict__ cnt,
                                                     int* __restrict__ bsum, int n) {
    const int tid = threadIdx.x;
    const int i = blockIdx.x * 256 + tid;
    int v = (i < n) ? cnt[i] : 0;
    int s = v;
#pragma unroll
    for (int d = 1; d < 64; d <<= 1) s += __shfl_xor(s, d);
    __shared__ int ws[4];
    if ((tid & 63) == 0) ws[tid >> 6] = s;
    __syncthreads();
    if (tid == 0) bsum[blockIdx.x] = ws[0] + ws[1] + ws[2] + ws[3];
}

// phase B: single small block scans nb block sums in place -> exclusive offsets
__global__ __launch_bounds__(256) void scan_b_kernel(int* __restrict__ bsum, int nb) {
    const int tid = threadIdx.x;
    int v = (tid < nb) ? bsum[tid] : 0;
    const int lane = tid & 63, wid = tid >> 6;
    int incl = v;
#pragma unroll
    for (int d = 1; d < 64; d <<= 1) { int m = __shfl_up(incl, d); if (lane >= d) incl += m; }
    __shared__ int ws[4];
    if (lane == 63) ws[wid] = incl;
    __syncthreads();
    if (tid < 4) {
        int wv = ws[tid];
        int iv = wv;
#pragma unroll
        for (int d = 1; d < 4; d <<= 1) { int m = __shfl_up(iv, d, 4); if (tid >= d) iv += m; }
        ws[tid] = iv - wv;
    }
    __syncthreads();
    if (tid < nb) bsum[tid] = (incl - v) + ws[wid];
}

// phase C: in-block exclusive scan + block offset -> rptr, cur; rptr[n] at tail
__global__ __launch_bounds__(256) void scan_c_kernel(const int* __restrict__ cnt,
                                                     const int* __restrict__ bsum,
                                                     int* __restrict__ rptr,
                                                     int* __restrict__ cur, int n) {
    const int tid = threadIdx.x;
    const int i = blockIdx.x * 256 + tid;
    int v = (i < n) ? cnt[i] : 0;
    const int lane = tid & 63, wid = tid >> 6;
    int incl = v;
#pragma unroll
    for (int d = 1; d < 64; d <<= 1) { int m = __shfl_up(incl, d); if (lane >= d) incl += m; }
    __shared__ int ws[4];
    if (lane == 63) ws[wid] = incl;
    __syncthreads();
    if (tid < 4) {
        int wv = ws[tid];
        int iv = wv;
#pragma unroll
        for (int d = 1; d < 4; d <<= 1) { int m = __shfl_up(iv, d, 4); if (tid >= d) iv += m; }
        ws[tid] = iv - wv;
    }
    __syncthreads();
    const int excl = (incl - v) + ws[wid] + bsum[blockIdx.x];
    if (i < n) { rptr[i] = excl; cur[i] = excl; }
    if (i == n - 1) rptr[n] = excl + v;
}

// bucket edges by dst; store raw (src, w) — NO dinv dependency
__global__ void fill_kernel(const int* __restrict__ src, const int* __restrict__ dst,
                            const float* __restrict__ w,
                            int* cur, uint2* __restrict__ edata, int ne) {
    int e = blockIdx.x * 256 + threadIdx.x;
    if (e < ne) {
        int d = dst[e];
        int pos = atomicAdd(&cur[d], 1);
        uint2 ed;
        ed.x = (unsigned)src[e];
        ed.y = __float_as_uint(w[e]);
        edata[pos] = ed;
    }
}

// per-node weighted degree from sorted edata (coalesced, no atomics) -> dinv
__global__ void deg_kernel(const uint2* __restrict__ edata, const int* __restrict__ rptr,
                           float* __restrict__ dinv, int n) {
    int v = blockIdx.x * 256 + threadIdx.x;
    if (v < n) {
        const int b = rptr[v], e = rptr[v + 1];
        float s = 1.0f;   // self-loop weight
        for (int i = b; i < e; ++i) s += __uint_as_float(edata[i].y);
        dinv[v] = s > 0.f ? rsqrtf(s) : 0.f;
    }
}

// one wave per dst node; 8 independent edge chains; norm computed at prefetch
__global__ __launch_bounds__(256) void agg_kernel(const ushort_t* __restrict__ Xb,
                                                  const int* __restrict__ rptr,
                                                  const uint2* __restrict__ edata,
                                                  const float* __restrict__ dinv,
                                                  ushort_t* __restrict__ out, int n) {
    const int v = blockIdx.x * 4 + (threadIdx.x >> 6);
    if (v >= n) return;
    const int lane = threadIdx.x & 63;
    const float dv = dinv[v];
    const uint2 xv = *(const uint2*)(Xb + (size_t)v * HDIM + lane * 4);
    const float dv2 = dv * dv;
    float a0[8], a1[8], a2[8], a3[8];
#pragma unroll
    for (int c = 0; c < 8; ++c) { a0[c] = 0.f; a1[c] = 0.f; a2[c] = 0.f; a3[c] = 0.f; }
    a0[0] = dv2 * bf_lo(xv.x); a1[0] = dv2 * bf_hi(xv.x);
    a2[0] = dv2 * bf_lo(xv.y); a3[0] = dv2 * bf_hi(xv.y);

    const int b = rptr[v];
    const int total = rptr[v + 1] - b;
    uint2 pv[8]; float pn[8];
#pragma unroll
    for (int c = 0; c < 8; ++c) {
        if (c < total) {
            uint2 ed = edata[b + c];
            pn[c] = dinv[ed.x] * __uint_as_float(ed.y) * dv;
            pv[c] = *(const uint2*)(Xb + (size_t)ed.x * HDIM + lane * 4);
        }
    }
    for (int base = 0; base < total; base += 8) {
#pragma unroll
        for (int c = 0; c < 8; ++c) {
            if (base + c < total) {
                uint2 cv = pv[c]; float cn = pn[c];
                int nx = base + 8 + c;
                if (nx < total) {
                    uint2 ed = edata[b + nx];
                    pn[c] = dinv[ed.x] * __uint_as_float(ed.y) * dv;
                    pv[c] = *(const uint2*)(Xb + (size_t)ed.x * HDIM + lane * 4);
                }
                a0[c] = fmaf(cn, bf_lo(cv.x), a0[c]);
                a1[c] = fmaf(cn, bf_hi(cv.x), a1[c]);
                a2[c] = fmaf(cn, bf_lo(cv.y), a2[c]);
                a3[c] = fmaf(cn, bf_hi(cv.y), a3[c]);
            }
        }
    }
    float r0 = ((a0[0] + a0[1]) + (a0[2] + a0[3])) + ((a0[4] + a0[5]) + (a0[6] + a0[7]));
    float r1 = ((a1[0] + a1[1]) + (a1[2] + a1[3])) + ((a1[4] + a1[5]) + (a1[6] + a1[7]));
    float r2 = ((a2[0] + a2[1]) + (a2[2] + a2[3])) + ((a2[4] + a2[5]) + (a2[6] + a2[7]));
    float r3 = ((a3[0] + a3[1]) + (a3[2] + a3[3])) + ((a3[4] + a3[5]) + (a3[6] + a3[7]));
    uint2 o;
    o.x = cvt_pk_bf16(r0, r1);
    o.y = cvt_pk_bf16(r2, r3);
    *(uint2*)(out + (size_t)v * HDIM + lane * 4) = o;
}

// ---------------- bf16 weight prep (generic, K -> KP padded) ----------------
__global__ void prep_w_kernel(const float* __restrict__ W, ushort_t* __restrict__ Wp,
                              int K, int KP) {
    int i = blockIdx.x * 256 + threadIdx.x;
    if (i < 256 * KP) {
        int n = i / KP, k = i - n * KP;
        Wp[i] = (k < K) ? f2bf(W[n * K + k]) : (ushort_t)0;
    }
}

// ---------------- edge MLP: persistent, dbuf LDS, FULL-ROWS-PER-WAVE ----------------
// Wave wv owns rows wv*16..+15 (all 256 cols): acc[nt] over nt<16,
// m = wv*16 + c, n = nt*16 + g*4 + reg. A row lives in 4 lanes (g=0..3)
// of one wave -> LN stats via 2 shfl_xor, NO epilogue LDS, 1 barrier/tile.
// W fragments stream from L1 (64KB table, read in lockstep by all waves).
__global__ __launch_bounds__(256) void mlp_mfma_kernel(
    const float* __restrict__ A,            // [M][107] f32
    const ushort_t* __restrict__ Wp,        // [256][128] bf16, zero-padded k>=107
    const float* __restrict__ b1v, const float* __restrict__ g1v,
    const float* __restrict__ be1v, const float* __restrict__ W2,
    const float* __restrict__ b2s, float* __restrict__ out,
    int M, int ntiles) {
    __shared__ ushort_t As[2][64][136];
    const int tid = threadIdx.x;
    const int l = tid & 63, wv = tid >> 6, g = l >> 4, c = l & 15;
    const float b2sc = b2s[0];
    const size_t tot = (size_t)M * KA;

    // one-time zero of k in [112,128) for BOTH buffers (staging never writes there;
    // k in [107,112) gets finite garbage each tile, killed by W zero-pad)
    for (int z = tid; z < 2 * 64 * 16; z += 256) {
        int buf = z >> 10;
        int rem = z & 1023;
        As[buf][rem >> 4][112 + (rem & 15)] = 0;
    }

    // staging role: 4 threads per row; thread (srow=tid>>2, sj=tid&3) covers k = sj*4 + i*16, i<7
    const int srow = tid >> 2, sj = tid & 3;
    float4 sreg[7];

    // ---- prologue: stage tile t0 into buf 0 ----
    const int t0 = blockIdx.x;
    if (t0 < ntiles) {
        const size_t roff = (size_t)(t0 * 64 + srow) * KA + sj * 4;
#pragma unroll
        for (int i = 0; i < 7; ++i) sreg[i] = guarded_load4(A, roff + i * 16, tot);
#pragma unroll
        for (int i = 0; i < 7; ++i) {
            uint2 o;
            o.x = cvt_pk_bf16(sreg[i].x, sreg[i].y);
            o.y = cvt_pk_bf16(sreg[i].z, sreg[i].w);
            *(uint2*)&As[0][srow][sj * 4 + i * 16] = o;
        }
    }
    __syncthreads();

    const int nb = g << 2;   // col offset within a 16-block
    int cur = 0;
    for (int t = t0; t < ntiles; t += gridDim.x) {
        const int tn = t + gridDim.x;
        const bool have_next = tn < ntiles;
        // (A) issue next tile's loads early (f32, consumed only at (E))
        if (have_next) {
            const size_t roff = (size_t)(tn * 64 + srow) * KA + sj * 4;
#pragma unroll
            for (int i = 0; i < 7; ++i) sreg[i] = guarded_load4(A, roff + i * 16, tot);
        }

        // (B) MFMA: wave's 16 rows x all 256 cols; A-frags reused across nt
        f32x4 acc[16];
#pragma unroll
        for (int nt = 0; nt < 16; ++nt) acc[nt] = (f32x4){0.f, 0.f, 0.f, 0.f};
        bf16x8 af[4];
#pragma unroll
        for (int ks = 0; ks < 4; ++ks)
            af[ks] = *(const bf16x8*)&As[cur][wv * 16 + c][ks * 32 + g * 8];
        __builtin_amdgcn_s_setprio(1);
#pragma unroll
        for (int nt = 0; nt < 16; ++nt) {
            const ushort_t* wb = Wp + (size_t)(nt * 16 + c) * KAP + g * 8;
#pragma unroll
            for (int ks = 0; ks < 4; ++ks) {
                bf16x8 wfr = *(const bf16x8*)(wb + ks * 32);
                acc[nt] = __builtin_amdgcn_mfma_f32_16x16x32_bf16(wfr, af[ks], acc[nt], 0, 0, 0);
            }
        }
        __builtin_amdgcn_s_setprio(0);

        // (C) epilogue, fully in-wave: bias add + stats + LN + relu + dot(W2)
        float s1 = 0.f, s2 = 0.f;
#pragma unroll
        for (int nt = 0; nt < 16; ++nt) {
            const float4 b4 = *(const float4*)(b1v + nt * 16 + nb);
            f32x4 v = acc[nt];
            v[0] += b4.x; v[1] += b4.y; v[2] += b4.z; v[3] += b4.w;
            acc[nt] = v;
            s1 += v[0] + v[1] + v[2] + v[3];
            s2 += v[0] * v[0] + v[1] * v[1] + v[2] * v[2] + v[3] * v[3];
        }
        s1 += __shfl_xor(s1, 16); s1 += __shfl_xor(s1, 32);
        s2 += __shfl_xor(s2, 16); s2 += __shfl_xor(s2, 32);
        const float mu = s1 * (1.f / HDIM);
        const float var = s2 * (1.f / HDIM) - mu * mu;
        const float rs = rsqrtf(var + 1e-5f);
        float dacc = 0.f;
#pragma unroll
        for (int nt = 0; nt < 16; ++nt) {
            const float4 g4 = *(const float4*)(g1v + nt * 16 + nb);
            const float4 e4 = *(const float4*)(be1v + nt * 16 + nb);
            const float4 w4 = *(const float4*)(W2 + nt * 16 + nb);
            f32x4 v = acc[nt];
            float y0 = fmaxf((v[0] - mu) * rs * g4.x + e4.x, 0.f);
            float y1 = fmaxf((v[1] - mu) * rs * g4.y + e4.y, 0.f);
            float y2 = fmaxf((v[2] - mu) * rs * g4.z + e4.z, 0.f);
            float y3 = fmaxf((v[3] - mu) * rs * g4.w + e4.w, 0.f);
            dacc = fmaf(y0, w4.x, dacc); dacc = fmaf(y1, w4.y, dacc);
            dacc = fmaf(y2, w4.z, dacc); dacc = fmaf(y3, w4.w, dacc);
        }
        dacc += __shfl_xor(dacc, 16); dacc += __shfl_xor(dacc, 32);
        if (l < 16) {
            int gr = t * 64 + wv * 16 + c;
            if (gr < M) out[gr] = dacc + b2sc;
        }

        // (E) cvt + write next buffer (vmcnt wait lands here, after MFMA+epilogue)
        if (have_next) {
#pragma unroll
            for (int i = 0; i < 7; ++i) {
                uint2 o;
                o.x = cvt_pk_bf16(sreg[i].x, sreg[i].y);
                o.y = cvt_pk_bf16(sreg[i].z, sreg[i].w);
                *(uint2*)&As[cur ^ 1][srow][sj * 4 + i * 16] = o;
            }
        }
        __syncthreads();   // single barrier: As[cur^1] complete; As[cur] reads done
        cur ^= 1;
    }
}

// ---------------- node GEMM: bf16 MFMA, C^T epilogue, fused LN(s), bf16 residuals ----------------
template <int MODE>
__global__ __launch_bounds__(256) void gemm_node_kernel(
    const ushort_t* __restrict__ A,
    const ushort_t* __restrict__ Wp,
    const float* __restrict__ bias,
    const ushort_t* __restrict__ res_bf,
    const ushort_t* __restrict__ orig_bf,
    const float* __restrict__ g1v, const float* __restrict__ b1v,
    const float* __restrict__ g2v, const float* __restrict__ b2v,
    float* __restrict__ out, ushort_t* __restrict__ out_bf, int M) {
    __shared__ ushort_t As[64][264];
    __shared__ float ps1[64][4], ps2[64][4], ps3[64][4], ps4[64][4];
    const int tid = threadIdx.x;
    const int m0 = blockIdx.x * 64;
    const int l = tid & 63, wv = tid >> 6, g = l >> 4, c = l & 15;

    {
        const int r = tid >> 2, j = tid & 3;
        const ushort_t* gsrc = A + (size_t)(m0 + r) * HDIM;
        const bool ok = (m0 + r) < M;
#pragma unroll
        for (int i = 0; i < 8; ++i) {
            const int ci = i * 4 + j;
            bf16x8 v = (bf16x8){0,0,0,0,0,0,0,0};
            if (ok) v = *(const bf16x8*)(gsrc + ci * 8);
            *(bf16x8*)&As[r][ci * 8] = v;
        }
    }
    __syncthreads();

    f32x4 acc[4][4];
#pragma unroll
    for (int rt = 0; rt < 4; ++rt)
#pragma unroll
        for (int nt = 0; nt < 4; ++nt) acc[rt][nt] = (f32x4){0.f, 0.f, 0.f, 0.f};

    const ushort_t* wb = Wp + (size_t)(wv * 64 + c) * HDIM + g * 8;
    __builtin_amdgcn_s_setprio(1);
#pragma unroll
    for (int ks = 0; ks < 8; ++ks) {
        bf16x8 af[4];
#pragma unroll
        for (int rt = 0; rt < 4; ++rt)
            af[rt] = *(const bf16x8*)&As[rt * 16 + c][ks * 32 + g * 8];
#pragma unroll
        for (int nt = 0; nt < 4; ++nt) {
            bf16x8 bfr = *(const bf16x8*)(wb + nt * 16 * HDIM + ks * 32);
#pragma unroll
            for (int rt = 0; rt < 4; ++rt)
                acc[rt][nt] = __builtin_amdgcn_mfma_f32_16x16x32_bf16(bfr, af[rt], acc[rt][nt], 0, 0, 0);
        }
    }
    __builtin_amdgcn_s_setprio(0);

    const int nb = wv * 64 + (g << 2);
#pragma unroll
    for (int rt = 0; rt < 4; ++rt) {
        const int m = m0 + rt * 16 + c;
        const bool vm = m < M;
        const ushort_t* rrow = res_bf + (size_t)m * HDIM + nb;
        float s1 = 0.f, s2 = 0.f;
#pragma unroll
        for (int nt = 0; nt < 4; ++nt) {
            const float4 b4 = *(const float4*)(bias + nb + nt * 16);
            float4 r4 = {0.f, 0.f, 0.f, 0.f};
            if (vm) {
                uint2 rb = *(const uint2*)(rrow + nt * 16);
                r4.x = bf_lo(rb.x); r4.y = bf_hi(rb.x);
                r4.z = bf_lo(rb.y); r4.w = bf_hi(rb.y);
            }
            f32x4 v = acc[rt][nt];
            v[0] += b4.x + r4.x; v[1] += b4.y + r4.y;
            v[2] += b4.z + r4.z; v[3] += b4.w + r4.w;
            acc[rt][nt] = v;
            s1 += v[0] + v[1] + v[2] + v[3];
            s2 += v[0] * v[0] + v[1] * v[1] + v[2] * v[2] + v[3] * v[3];
        }
        s1 += __shfl_xor(s1, 16); s1 += __shfl_xor(s1, 32);
        s2 += __shfl_xor(s2, 16); s2 += __shfl_xor(s2, 32);
        if (l < 16) { ps1[rt * 16 + c][wv] = s1; ps2[rt * 16 + c][wv] = s2; }
    }
    __syncthreads();
#pragma unroll
    for (int rt = 0; rt < 4; ++rt) {
        const int m = m0 + rt * 16 + c;
        const bool vm = m < M;
        float4 p1 = *(const float4*)ps1[rt * 16 + c];
        float4 p2 = *(const float4*)ps2[rt * 16 + c];
        float s1 = p1.x + p1.y + p1.z + p1.w;
        float s2 = p2.x + p2.y + p2.z + p2.w;
        float mu = s1 * (1.f / HDIM);
        float var = s2 * (1.f / HDIM) - mu * mu;
        float rs = rsqrtf(var + 1e-5f);
        if constexpr (MODE == 0) {
            ushort_t* obrow = out_bf + (size_t)m * HDIM + nb;
#pragma unroll
            for (int nt = 0; nt < 4; ++nt) {
                const float4 g4 = *(const float4*)(g1v + nb + nt * 16);
                const float4 e4 = *(const float4*)(b1v + nb + nt * 16);
                f32x4 v = acc[rt][nt];
                float o0 = fmaxf((v[0] - mu) * rs * g4.x + e4.x, 0.f);
                float o1 = fmaxf((v[1] - mu) * rs * g4.y + e4.y, 0.f);
                float o2 = fmaxf((v[2] - mu) * rs * g4.z + e4.z, 0.f);
                float o3 = fmaxf((v[3] - mu) * rs * g4.w + e4.w, 0.f);
                if (vm) {
                    uint2 ob;
                    ob.x = cvt_pk_bf16(o0, o1);
                    ob.y = cvt_pk_bf16(o2, o3);
                    *(uint2*)(obrow + nt * 16) = ob;
                }
            }
        } else {
            const ushort_t* grow = orig_bf + (size_t)m * HDIM + nb;
            float t1 = 0.f, t2 = 0.f;
#pragma unroll
            for (int nt = 0; nt < 4; ++nt) {
                const float4 g4 = *(const float4*)(g1v + nb + nt * 16);
                const float4 e4 = *(const float4*)(b1v + nb + nt * 16);
                float4 o4 = {0.f, 0.f, 0.f, 0.f};
                if (vm) {
                    uint2 gb = *(const uint2*)(grow + nt * 16);
                    o4.x = bf_lo(gb.x); o4.y = bf_hi(gb.x);
                    o4.z = bf_lo(gb.y); o4.w = bf_hi(gb.y);
                }
                f32x4 v = acc[rt][nt];
                f32x4 u;
                u[0] = fmaxf((v[0] - mu) * rs * g4.x + e4.x, 0.f) + o4.x;
                u[1] = fmaxf((v[1] - mu) * rs * g4.y + e4.y, 0.f) + o4.y;
                u[2] = fmaxf((v[2] - mu) * rs * g4.z + e4.z, 0.f) + o4.z;
                u[3] = fmaxf((v[3] - mu) * rs * g4.w + e4.w, 0.f) + o4.w;
                acc[rt][nt] = u;
                t1 += u[0] + u[1] + u[2] + u[3];
                t2 += u[0] * u[0] + u[1] * u[1] + u[2] * u[2] + u[3] * u[3];
            }
            t1 += __shfl_xor(t1, 16); t1 += __shfl_xor(t1, 32);
            t2 += __shfl_xor(t2, 16); t2 += __shfl_xor(t2, 32);
            if (l < 16) { ps3[rt * 16 + c][wv] = t1; ps4[rt * 16 + c][wv] = t2; }
        }
    }
    if constexpr (MODE == 1) {
        __syncthreads();
#pragma unroll
        for (int rt = 0; rt < 4; ++rt) {
            const int m = m0 + rt * 16 + c;
            const bool vm = m < M;
            float4 p1 = *(const float4*)ps3[rt * 16 + c];
            float4 p2 = *(const float4*)ps4[rt * 16 + c];
            float s1 = p1.x + p1.y + p1.z + p1.w;
            float s2 = p2.x + p2.y + p2.z + p2.w;
            float mu2 = s1 * (1.f / HDIM);
            float var2 = s2 * (1.f / HDIM) - mu2 * mu2;
            float rs2 = rsqrtf(var2 + 1e-5f);
            float* orow = out + (size_t)m * HDIM + nb;
#pragma unroll
            for (int nt = 0; nt < 4; ++nt) {
                const float4 g4 = *(const float4*)(g2v + nb + nt * 16);
                const float4 e4 = *(const float4*)(b2v + nb + nt * 16);
                f32x4 u = acc[rt][nt];
                float4 o;
                o.x = (u[0] - mu2) * rs2 * g4.x + e4.x;
                o.y = (u[1] - mu2) * rs2 * g4.y + e4.y;
                o.z = (u[2] - mu2) * rs2 * g4.z + e4.z;
                o.w = (u[3] - mu2) * rs2 * g4.w + e4.w;
                if (vm) *(float4*)(orow + nt * 16) = o;
            }
        }
    }
}

// ---------------- launch ----------------

extern "C" void kernel_launch(void* const* d_in, const int* in_sizes, int n_in,
                              void* d_out, int out_size, void* d_ws, size_t ws_size,
                              hipStream_t stream) {
    const float* x    = (const float*)d_in[0];
    const int*   eib  = (const int*)d_in[1];
    const float* eab  = (const float*)d_in[2];
    const int*   eit  = (const int*)d_in[3];
    const float* eat  = (const float*)d_in[4];
    const float* Wb   = (const float*)d_in[5];
    const float* bb   = (const float*)d_in[6];
    const float* Wt   = (const float*)d_in[7];
    const float* bt   = (const float*)d_in[8];
    const float* W1   = (const float*)d_in[9];
    const float* b1   = (const float*)d_in[10];
    const float* g1   = (const float*)d_in[11];
    const float* be1  = (const float*)d_in[12];
    const float* W2   = (const float*)d_in[13];
    const float* b2   = (const float*)d_in[14];
    const float* gs   = (const float*)d_in[15];
    const float* bs   = (const float*)d_in[16];
    const float* gt   = (const float*)d_in[17];
    const float* btn  = (const float*)d_in[18];

    const int Nn = in_sizes[0] / HDIM;     // 50000
    const int Ne = in_sizes[2];            // 800000

    const int* src_b = eib;  const int* dst_b = eib + Ne;
    const int* src_t = eit;  const int* dst_t = eit + Ne;

    char* w = (char*)d_ws;
    ushort_t* aggb = (ushort_t*)w; w += (size_t)Nn * HDIM * 2;
    ushort_t* xb   = (ushort_t*)w; w += (size_t)Nn * HDIM * 2;
    ushort_t* x1b  = (ushort_t*)w; w += (size_t)Nn * HDIM * 2;
    float*    wtmp = (float*)w;    w += (size_t)Ne * 4;
    float*    dinv = (float*)w;    w += (size_t)Nn * 4;
    int*      cnt  = (int*)w;      w += (size_t)Nn * 4;
    int*      rptr = (int*)w;      w += (size_t)(Nn + 4) * 4;
    int*      cur  = (int*)w;      w += (size_t)Nn * 4;
    uint2*    edata = (uint2*)w;   w += (size_t)Ne * 8;
    int*      bsum = (int*)w;      w += (size_t)256 * 4;
    ushort_t* W1p  = (ushort_t*)w; w += (size_t)256 * KAP * 2;
    ushort_t* Wbp  = (ushort_t*)w; w += (size_t)256 * 256 * 2;
    ushort_t* Wtp  = (ushort_t*)w; w += (size_t)256 * 256 * 2;

    float* out = (float*)d_out;
    dim3 b256(256);
    dim3 gN((Nn + 255) / 256), gE((Ne + 255) / 256);
    const int nbScan = (Nn + 255) / 256;
    dim3 gAgg((Nn + 3) / 4);
    dim3 gGemmN((Nn + 63) / 64);
    const int ntiles = (Ne + 63) / 64;
    dim3 gMlp(1024);
    const int n4 = Nn * HDIM / 4;
    dim3 gCvt((n4 + 255) / 256);

    // ---- weight prep (bf16) ----
    prep_w_kernel<<<dim3((256 * KAP + 255) / 256), b256, 0, stream>>>(W1, W1p, KA, KAP);
    prep_w_kernel<<<dim3((256 * 256 + 255) / 256), b256, 0, stream>>>(Wb, Wbp, 256, 256);
    prep_w_kernel<<<dim3((256 * 256 + 255) / 256), b256, 0, stream>>>(Wt, Wtp, 256, 256);
    f32_to_bf16_kernel<<<gCvt, b256, 0, stream>>>(x, xb, n4);

    // ---- stage A: BOLD GCN ----
    hipMemsetAsync(cnt, 0, (size_t)Nn * 4, stream);
    hist_cnt_kernel<<<gE, b256, 0, stream>>>(dst_b, cnt, Ne);
    scan_a_kernel<<<dim3(nbScan), b256, 0, stream>>>(cnt, bsum, Nn);
    scan_b_kernel<<<dim3(1), b256, 0, stream>>>(bsum, nbScan);
    scan_c_kernel<<<dim3(nbScan), b256, 0, stream>>>(cnt, bsum, rptr, cur, Nn);
    fill_kernel<<<gE, b256, 0, stream>>>(src_b, dst_b, eab, cur, edata, Ne);
    deg_kernel<<<gN, b256, 0, stream>>>(edata, rptr, dinv, Nn);
    agg_kernel<<<gAgg, b256, 0, stream>>>(xb, rptr, edata, dinv, aggb, Nn);
    gemm_node_kernel<0><<<gGemmN, b256, 0, stream>>>(
        aggb, Wbp, bb, xb, nullptr, gs, bs, nullptr, nullptr, nullptr, x1b, Nn);

    // ---- temporal edge-weight MLP (persistent, full-rows-per-wave) ----
    mlp_mfma_kernel<<<gMlp, b256, 0, stream>>>(
        eat, W1p, b1, g1, be1, W2, b2, wtmp, Ne, ntiles);

    // ---- stage B: temporal GCN + final LN ----
    hipMemsetAsync(cnt, 0, (size_t)Nn * 4, stream);
    hist_cnt_kernel<<<gE, b256, 0, stream>>>(dst_t, cnt, Ne);
    scan_a_kernel<<<dim3(nbScan), b256, 0, stream>>>(cnt, bsum, Nn);
    scan_b_kernel<<<dim3(1), b256, 0, stream>>>(bsum, nbScan);
    scan_c_kernel<<<dim3(nbScan), b256, 0, stream>>>(cnt, bsum, rptr, cur, Nn);
    fill_kernel<<<gE, b256, 0, stream>>>(src_t, dst_t, wtmp, cur, edata, Ne);
    deg_kernel<<<gN, b256, 0, stream>>>(edata, rptr, dinv, Nn);
    agg_kernel<<<gAgg, b256, 0, stream>>>(x1b, rptr, edata, dinv, aggb, Nn);
    gemm_node_kernel<1><<<gGemmN, b256, 0, stream>>>(
        aggb, Wtp, bt, x1b, xb, gt, btn, gs, bs, out, nullptr, Nn);
}

// Round 15
// 778.672 us; speedup vs baseline: 2.0180x; 2.0180x over previous
//
#include <hip/hip_runtime.h>

#define HDIM 256
#define KA 107
#define KAP 128

typedef short bf16x8 __attribute__((ext_vector_type(8)));
typedef float f32x4 __attribute__((ext_vector_type(4)));
typedef unsigned short ushort_t;

__device__ inline unsigned short f2bf(float f) {
    union { float f; unsigned u; } v; v.f = f;
    unsigned r = v.u + 0x7fff + ((v.u >> 16) & 1);
    return (unsigned short)(r >> 16);
}

__device__ inline unsigned cvt_pk_bf16(float a, float b) {
    unsigned r;
    asm("v_cvt_pk_bf16_f32 %0, %1, %2" : "=v"(r) : "v"(a), "v"(b));
    return r;   // low16 = bf16(a), high16 = bf16(b)
}

__device__ inline float bf_lo(unsigned u) { union { unsigned v; float f; } x; x.v = u << 16; return x.f; }
__device__ inline float bf_hi(unsigned u) { union { unsigned v; float f; } x; x.v = u & 0xffff0000u; return x.f; }

__device__ inline float4 guarded_load4(const float* p, size_t off, size_t tot) {
    if (off + 4 <= tot) return *(const float4*)(p + off);
    float4 r = {0.f, 0.f, 0.f, 0.f};
    float* rr = (float*)&r;
    for (int e = 0; e < 4; ++e) if (off + e < tot) rr[e] = p[off + e];
    return r;
}

// ---------------- small kernels ----------------

// count histogram only (1 atomic per edge)
__global__ void hist_cnt_kernel(const int* __restrict__ dst, int* cnt, int ne) {
    int e = blockIdx.x * 256 + threadIdx.x;
    if (e < ne) atomicAdd(&cnt[dst[e]], 1);
}

// f32 -> bf16 mirror (float4 -> uint2)
__global__ void f32_to_bf16_kernel(const float* __restrict__ in, ushort_t* __restrict__ out, int n4) {
    int i = blockIdx.x * 256 + threadIdx.x;
    if (i < n4) {
        float4 v = ((const float4*)in)[i];
        uint2 o;
        o.x = cvt_pk_bf16(v.x, v.y);
        o.y = cvt_pk_bf16(v.z, v.w);
        ((uint2*)out)[i] = o;
    }
}

// fused bf16 prep for W1 (107->128 pad), Wb (256), Wt (256)
__global__ void prep_all_w_kernel(const float* __restrict__ W1, ushort_t* __restrict__ W1p,
                                  const float* __restrict__ Wb, ushort_t* __restrict__ Wbp,
                                  const float* __restrict__ Wt, ushort_t* __restrict__ Wtp) {
    const int n1 = 256 * KAP, n2 = 256 * 256;
    int i = blockIdx.x * 256 + threadIdx.x;
    if (i < n1) {
        int n = i >> 7, k = i & (KAP - 1);
        W1p[i] = (k < KA) ? f2bf(W1[n * KA + k]) : (ushort_t)0;
    } else if (i < n1 + n2) {
        int j = i - n1;
        Wbp[j] = f2bf(Wb[j]);
    } else if (i < n1 + 2 * n2) {
        int j = i - n1 - n2;
        Wtp[j] = f2bf(Wt[j]);
    }
}

// ---------------- multi-block scan (3 phases) ----------------
// phase A: per-block sum of cnt[256] -> bsum[bid]
__global__ __launch_bounds__(256) void scan_a_kernel(const int* __restrict__ cnt,
                                                     int* __restrict__ bsum, int n) {
    const int tid = threadIdx.x;
    const int i = blockIdx.x * 256 + tid;
    int v = (i < n) ? cnt[i] : 0;
    int s = v;
#pragma unroll
    for (int d = 1; d < 64; d <<= 1) s += __shfl_xor(s, d);
    __shared__ int ws[4];
    if ((tid & 63) == 0) ws[tid >> 6] = s;
    __syncthreads();
    if (tid == 0) bsum[blockIdx.x] = ws[0] + ws[1] + ws[2] + ws[3];
}

// phase B: single small block scans nb block sums in place -> exclusive offsets
__global__ __launch_bounds__(256) void scan_b_kernel(int* __restrict__ bsum, int nb) {
    const int tid = threadIdx.x;
    int v = (tid < nb) ? bsum[tid] : 0;
    const int lane = tid & 63, wid = tid >> 6;
    int incl = v;
#pragma unroll
    for (int d = 1; d < 64; d <<= 1) { int m = __shfl_up(incl, d); if (lane >= d) incl += m; }
    __shared__ int ws[4];
    if (lane == 63) ws[wid] = incl;
    __syncthreads();
    if (tid < 4) {
        int wv = ws[tid];
        int iv = wv;
#pragma unroll
        for (int d = 1; d < 4; d <<= 1) { int m = __shfl_up(iv, d, 4); if (tid >= d) iv += m; }
        ws[tid] = iv - wv;
    }
    __syncthreads();
    if (tid < nb) bsum[tid] = (incl - v) + ws[wid];
}

// phase C: in-block exclusive scan + block offset -> rptr, cur; rptr[n] at tail
__global__ __launch_bounds__(256) void scan_c_kernel(const int* __restrict__ cnt,
                                                     const int* __restrict__ bsum,
                                                     int* __restrict__ rptr,
                                                     int* __restrict__ cur, int n) {
    const int tid = threadIdx.x;
    const int i = blockIdx.x * 256 + tid;
    int v = (i < n) ? cnt[i] : 0;
    const int lane = tid & 63, wid = tid >> 6;
    int incl = v;
#pragma unroll
    for (int d = 1; d < 64; d <<= 1) { int m = __shfl_up(incl, d); if (lane >= d) incl += m; }
    __shared__ int ws[4];
    if (lane == 63) ws[wid] = incl;
    __syncthreads();
    if (tid < 4) {
        int wv = ws[tid];
        int iv = wv;
#pragma unroll
        for (int d = 1; d < 4; d <<= 1) { int m = __shfl_up(iv, d, 4); if (tid >= d) iv += m; }
        ws[tid] = iv - wv;
    }
    __syncthreads();
    const int excl = (incl - v) + ws[wid] + bsum[blockIdx.x];
    if (i < n) { rptr[i] = excl; cur[i] = excl; }
    if (i == n - 1) rptr[n] = excl + v;
}

// bucket edges by dst; store raw (src, w) — NO dinv dependency
__global__ void fill_kernel(const int* __restrict__ src, const int* __restrict__ dst,
                            const float* __restrict__ w,
                            int* cur, uint2* __restrict__ edata, int ne) {
    int e = blockIdx.x * 256 + threadIdx.x;
    if (e < ne) {
        int d = dst[e];
        int pos = atomicAdd(&cur[d], 1);
        uint2 ed;
        ed.x = (unsigned)src[e];
        ed.y = __float_as_uint(w[e]);
        edata[pos] = ed;
    }
}

// per-node weighted degree from sorted edata (coalesced, no atomics) -> dinv
__global__ void deg_kernel(const uint2* __restrict__ edata, const int* __restrict__ rptr,
                           float* __restrict__ dinv, int n) {
    int v = blockIdx.x * 256 + threadIdx.x;
    if (v < n) {
        const int b = rptr[v], e = rptr[v + 1];
        float s = 1.0f;   // self-loop weight
        for (int i = b; i < e; ++i) s += __uint_as_float(edata[i].y);
        dinv[v] = s > 0.f ? rsqrtf(s) : 0.f;
    }
}

// one wave per dst node; 8 independent edge chains; norm computed at prefetch
__global__ __launch_bounds__(256) void agg_kernel(const ushort_t* __restrict__ Xb,
                                                  const int* __restrict__ rptr,
                                                  const uint2* __restrict__ edata,
                                                  const float* __restrict__ dinv,
                                                  ushort_t* __restrict__ out, int n) {
    const int v = blockIdx.x * 4 + (threadIdx.x >> 6);
    if (v >= n) return;
    const int lane = threadIdx.x & 63;
    const float dv = dinv[v];
    const uint2 xv = *(const uint2*)(Xb + (size_t)v * HDIM + lane * 4);
    const float dv2 = dv * dv;
    float a0[8], a1[8], a2[8], a3[8];
#pragma unroll
    for (int c = 0; c < 8; ++c) { a0[c] = 0.f; a1[c] = 0.f; a2[c] = 0.f; a3[c] = 0.f; }
    a0[0] = dv2 * bf_lo(xv.x); a1[0] = dv2 * bf_hi(xv.x);
    a2[0] = dv2 * bf_lo(xv.y); a3[0] = dv2 * bf_hi(xv.y);

    const int b = rptr[v];
    const int total = rptr[v + 1] - b;
    uint2 pv[8]; float pn[8];
#pragma unroll
    for (int c = 0; c < 8; ++c) {
        if (c < total) {
            uint2 ed = edata[b + c];
            pn[c] = dinv[ed.x] * __uint_as_float(ed.y) * dv;
            pv[c] = *(const uint2*)(Xb + (size_t)ed.x * HDIM + lane * 4);
        }
    }
    for (int base = 0; base < total; base += 8) {
#pragma unroll
        for (int c = 0; c < 8; ++c) {
            if (base + c < total) {
                uint2 cv = pv[c]; float cn = pn[c];
                int nx = base + 8 + c;
                if (nx < total) {
                    uint2 ed = edata[b + nx];
                    pn[c] = dinv[ed.x] * __uint_as_float(ed.y) * dv;
                    pv[c] = *(const uint2*)(Xb + (size_t)ed.x * HDIM + lane * 4);
                }
                a0[c] = fmaf(cn, bf_lo(cv.x), a0[c]);
                a1[c] = fmaf(cn, bf_hi(cv.x), a1[c]);
                a2[c] = fmaf(cn, bf_lo(cv.y), a2[c]);
                a3[c] = fmaf(cn, bf_hi(cv.y), a3[c]);
            }
        }
    }
    float r0 = ((a0[0] + a0[1]) + (a0[2] + a0[3])) + ((a0[4] + a0[5]) + (a0[6] + a0[7]));
    float r1 = ((a1[0] + a1[1]) + (a1[2] + a1[3])) + ((a1[4] + a1[5]) + (a1[6] + a1[7]));
    float r2 = ((a2[0] + a2[1]) + (a2[2] + a2[3])) + ((a2[4] + a2[5]) + (a2[6] + a2[7]));
    float r3 = ((a3[0] + a3[1]) + (a3[2] + a3[3])) + ((a3[4] + a3[5]) + (a3[6] + a3[7]));
    uint2 o;
    o.x = cvt_pk_bf16(r0, r1);
    o.y = cvt_pk_bf16(r2, r3);
    *(uint2*)(out + (size_t)v * HDIM + lane * 4) = o;
}

// ---------------- edge MLP: persistent, dbuf LDS, row-wise f32 staging (late cvt), W in regs ----------------
// R5/R13-validated config: f32 sreg defers vmcnt wait to the LDS-write phase;
// wreg hoist removes L1 loads from the MFMA critical path. 184 VGPR, no spill.
__global__ __launch_bounds__(256) void mlp_mfma_kernel(
    const float* __restrict__ A,            // [M][107] f32
    const ushort_t* __restrict__ Wp,        // [256][128] bf16, zero-padded k>=107
    const float* __restrict__ b1v, const float* __restrict__ g1v,
    const float* __restrict__ be1v, const float* __restrict__ W2,
    const float* __restrict__ b2s, float* __restrict__ out,
    int M, int ntiles) {
    __shared__ ushort_t As[2][64][136];
    __shared__ float ps1[64][4], ps2[64][4], pd[64][4];
    const int tid = threadIdx.x;
    const int l = tid & 63, wv = tid >> 6, g = l >> 4, c = l & 15;
    const float b2sc = b2s[0];
    const size_t tot = (size_t)M * KA;

    // one-time zero of k in [112,128) for BOTH buffers (staging never writes there;
    // k in [107,112) gets finite garbage each tile, killed by W zero-pad)
    for (int z = tid; z < 2 * 64 * 16; z += 256) {
        int buf = z >> 10;
        int rem = z & 1023;
        As[buf][rem >> 4][112 + (rem & 15)] = 0;
    }

    // hoist all W fragments (loop-invariant): wreg[ks][nt]
    bf16x8 wreg[4][4];
    {
        const ushort_t* wb = Wp + (size_t)(wv * 64 + c) * KAP + g * 8;
#pragma unroll
        for (int ks = 0; ks < 4; ++ks)
#pragma unroll
            for (int nt = 0; nt < 4; ++nt)
                wreg[ks][nt] = *(const bf16x8*)(wb + nt * 16 * KAP + ks * 32);
    }

    // staging role: 4 threads per row; thread (srow=tid>>2, sj=tid&3) covers k = sj*4 + i*16, i<7
    const int srow = tid >> 2, sj = tid & 3;
    float4 sreg[7];

    // ---- prologue: stage tile t0 into buf 0 ----
    const int t0 = blockIdx.x;
    if (t0 < ntiles) {
        const size_t roff = (size_t)(t0 * 64 + srow) * KA + sj * 4;
#pragma unroll
        for (int i = 0; i < 7; ++i) sreg[i] = guarded_load4(A, roff + i * 16, tot);
#pragma unroll
        for (int i = 0; i < 7; ++i) {
            uint2 o;
            o.x = cvt_pk_bf16(sreg[i].x, sreg[i].y);
            o.y = cvt_pk_bf16(sreg[i].z, sreg[i].w);
            *(uint2*)&As[0][srow][sj * 4 + i * 16] = o;
        }
    }
    __syncthreads();

    int cur = 0;
    for (int t = t0; t < ntiles; t += gridDim.x) {
        const int tn = t + gridDim.x;
        const bool have_next = tn < ntiles;
        // (A) issue next tile's loads early (f32, consumed only at (E))
        if (have_next) {
            const size_t roff = (size_t)(tn * 64 + srow) * KA + sj * 4;
#pragma unroll
            for (int i = 0; i < 7; ++i) sreg[i] = guarded_load4(A, roff + i * 16, tot);
        }

        // (B) MFMA on As[cur], W from registers
        f32x4 acc[4][4];
#pragma unroll
        for (int rt = 0; rt < 4; ++rt)
#pragma unroll
            for (int nt = 0; nt < 4; ++nt) acc[rt][nt] = (f32x4){0.f, 0.f, 0.f, 0.f};
        __builtin_amdgcn_s_setprio(1);
#pragma unroll
        for (int ks = 0; ks < 4; ++ks) {
            bf16x8 af[4];
#pragma unroll
            for (int rt = 0; rt < 4; ++rt)
                af[rt] = *(const bf16x8*)&As[cur][rt * 16 + c][ks * 32 + g * 8];
#pragma unroll
            for (int nt = 0; nt < 4; ++nt)
#pragma unroll
                for (int rt = 0; rt < 4; ++rt)
                    acc[rt][nt] = __builtin_amdgcn_mfma_f32_16x16x32_bf16(wreg[ks][nt], af[rt], acc[rt][nt], 0, 0, 0);
        }
        __builtin_amdgcn_s_setprio(0);

        const int nb = wv * 64 + (g << 2);
        const int m0 = t * 64;
        // (C) pass 1: bias + row sums
#pragma unroll
        for (int rt = 0; rt < 4; ++rt) {
            float s1 = 0.f, s2 = 0.f;
#pragma unroll
            for (int nt = 0; nt < 4; ++nt) {
                const float4 b4 = *(const float4*)(b1v + nb + nt * 16);
                f32x4 v = acc[rt][nt];
                v[0] += b4.x; v[1] += b4.y; v[2] += b4.z; v[3] += b4.w;
                acc[rt][nt] = v;
                s1 += v[0] + v[1] + v[2] + v[3];
                s2 += v[0] * v[0] + v[1] * v[1] + v[2] * v[2] + v[3] * v[3];
            }
            s1 += __shfl_xor(s1, 16); s1 += __shfl_xor(s1, 32);
            s2 += __shfl_xor(s2, 16); s2 += __shfl_xor(s2, 32);
            if (l < 16) { ps1[rt * 16 + c][wv] = s1; ps2[rt * 16 + c][wv] = s2; }
        }
        __syncthreads();   // barrier 1: ps published
        // (D) pass 2: LN + relu + dot(W2) -> pd
#pragma unroll
        for (int rt = 0; rt < 4; ++rt) {
            float4 p1 = *(const float4*)ps1[rt * 16 + c];
            float4 p2 = *(const float4*)ps2[rt * 16 + c];
            float s1 = p1.x + p1.y + p1.z + p1.w;
            float s2 = p2.x + p2.y + p2.z + p2.w;
            float mu = s1 * (1.f / HDIM);
            float var = s2 * (1.f / HDIM) - mu * mu;
            float rs = rsqrtf(var + 1e-5f);
            float dacc = 0.f;
#pragma unroll
            for (int nt = 0; nt < 4; ++nt) {
                const float4 g4 = *(const float4*)(g1v + nb + nt * 16);
                const float4 e4 = *(const float4*)(be1v + nb + nt * 16);
                const float4 w4 = *(const float4*)(W2 + nb + nt * 16);
                f32x4 v = acc[rt][nt];
                float y0 = fmaxf((v[0] - mu) * rs * g4.x + e4.x, 0.f);
                float y1 = fmaxf((v[1] - mu) * rs * g4.y + e4.y, 0.f);
                float y2 = fmaxf((v[2] - mu) * rs * g4.z + e4.z, 0.f);
                float y3 = fmaxf((v[3] - mu) * rs * g4.w + e4.w, 0.f);
                dacc = fmaf(y0, w4.x, dacc); dacc = fmaf(y1, w4.y, dacc);
                dacc = fmaf(y2, w4.z, dacc); dacc = fmaf(y3, w4.w, dacc);
            }
            dacc += __shfl_xor(dacc, 16); dacc += __shfl_xor(dacc, 32);
            if (l < 16) pd[rt * 16 + c][wv] = dacc;
        }
        // (E) cvt + write next buffer (vmcnt wait lands HERE, after MFMA+epilogue)
        if (have_next) {
#pragma unroll
            for (int i = 0; i < 7; ++i) {
                uint2 o;
                o.x = cvt_pk_bf16(sreg[i].x, sreg[i].y);
                o.y = cvt_pk_bf16(sreg[i].z, sreg[i].w);
                *(uint2*)&As[cur ^ 1][srow][sj * 4 + i * 16] = o;
            }
        }
        __syncthreads();   // barrier 2: pd published + As[cur^1] complete
        // (F) out store for tile t
        if (tid < 64) {
            float4 p = *(const float4*)pd[tid];
            int gr = m0 + tid;
            if (gr < M) out[gr] = p.x + p.y + p.z + p.w + b2sc;
        }
        cur ^= 1;
    }
}

// ---------------- node GEMM: bf16 MFMA, C^T epilogue, fused LN(s), bf16 residuals ----------------
template <int MODE>
__global__ __launch_bounds__(256) void gemm_node_kernel(
    const ushort_t* __restrict__ A,
    const ushort_t* __restrict__ Wp,
    const float* __restrict__ bias,
    const ushort_t* __restrict__ res_bf,
    const ushort_t* __restrict__ orig_bf,
    const float* __restrict__ g1v, const float* __restrict__ b1v,
    const float* __restrict__ g2v, const float* __restrict__ b2v,
    float* __restrict__ out, ushort_t* __restrict__ out_bf, int M) {
    __shared__ ushort_t As[64][264];
    __shared__ float ps1[64][4], ps2[64][4], ps3[64][4], ps4[64][4];
    const int tid = threadIdx.x;
    const int m0 = blockIdx.x * 64;
    const int l = tid & 63, wv = tid >> 6, g = l >> 4, c = l & 15;

    {
        const int r = tid >> 2, j = tid & 3;
        const ushort_t* gsrc = A + (size_t)(m0 + r) * HDIM;
        const bool ok = (m0 + r) < M;
#pragma unroll
        for (int i = 0; i < 8; ++i) {
            const int ci = i * 4 + j;
            bf16x8 v = (bf16x8){0,0,0,0,0,0,0,0};
            if (ok) v = *(const bf16x8*)(gsrc + ci * 8);
            *(bf16x8*)&As[r][ci * 8] = v;
        }
    }
    __syncthreads();

    f32x4 acc[4][4];
#pragma unroll
    for (int rt = 0; rt < 4; ++rt)
#pragma unroll
        for (int nt = 0; nt < 4; ++nt) acc[rt][nt] = (f32x4){0.f, 0.f, 0.f, 0.f};

    const ushort_t* wb = Wp + (size_t)(wv * 64 + c) * HDIM + g * 8;
    __builtin_amdgcn_s_setprio(1);
#pragma unroll
    for (int ks = 0; ks < 8; ++ks) {
        bf16x8 af[4];
#pragma unroll
        for (int rt = 0; rt < 4; ++rt)
            af[rt] = *(const bf16x8*)&As[rt * 16 + c][ks * 32 + g * 8];
#pragma unroll
        for (int nt = 0; nt < 4; ++nt) {
            bf16x8 bfr = *(const bf16x8*)(wb + nt * 16 * HDIM + ks * 32);
#pragma unroll
            for (int rt = 0; rt < 4; ++rt)
                acc[rt][nt] = __builtin_amdgcn_mfma_f32_16x16x32_bf16(bfr, af[rt], acc[rt][nt], 0, 0, 0);
        }
    }
    __builtin_amdgcn_s_setprio(0);

    const int nb = wv * 64 + (g << 2);
#pragma unroll
    for (int rt = 0; rt < 4; ++rt) {
        const int m = m0 + rt * 16 + c;
        const bool vm = m < M;
        const ushort_t* rrow = res_bf + (size_t)m * HDIM + nb;
        float s1 = 0.f, s2 = 0.f;
#pragma unroll
        for (int nt = 0; nt < 4; ++nt) {
            const float4 b4 = *(const float4*)(bias + nb + nt * 16);
            float4 r4 = {0.f, 0.f, 0.f, 0.f};
            if (vm) {
                uint2 rb = *(const uint2*)(rrow + nt * 16);
                r4.x = bf_lo(rb.x); r4.y = bf_hi(rb.x);
                r4.z = bf_lo(rb.y); r4.w = bf_hi(rb.y);
            }
            f32x4 v = acc[rt][nt];
            v[0] += b4.x + r4.x; v[1] += b4.y + r4.y;
            v[2] += b4.z + r4.z; v[3] += b4.w + r4.w;
            acc[rt][nt] = v;
            s1 += v[0] + v[1] + v[2] + v[3];
            s2 += v[0] * v[0] + v[1] * v[1] + v[2] * v[2] + v[3] * v[3];
        }
        s1 += __shfl_xor(s1, 16); s1 += __shfl_xor(s1, 32);
        s2 += __shfl_xor(s2, 16); s2 += __shfl_xor(s2, 32);
        if (l < 16) { ps1[rt * 16 + c][wv] = s1; ps2[rt * 16 + c][wv] = s2; }
    }
    __syncthreads();
#pragma unroll
    for (int rt = 0; rt < 4; ++rt) {
        const int m = m0 + rt * 16 + c;
        const bool vm = m < M;
        float4 p1 = *(const float4*)ps1[rt * 16 + c];
        float4 p2 = *(const float4*)ps2[rt * 16 + c];
        float s1 = p1.x + p1.y + p1.z + p1.w;
        float s2 = p2.x + p2.y + p2.z + p2.w;
        float mu = s1 * (1.f / HDIM);
        float var = s2 * (1.f / HDIM) - mu * mu;
        float rs = rsqrtf(var + 1e-5f);
        if constexpr (MODE == 0) {
            ushort_t* obrow = out_bf + (size_t)m * HDIM + nb;
#pragma unroll
            for (int nt = 0; nt < 4; ++nt) {
                const float4 g4 = *(const float4*)(g1v + nb + nt * 16);
                const float4 e4 = *(const float4*)(b1v + nb + nt * 16);
                f32x4 v = acc[rt][nt];
                float o0 = fmaxf((v[0] - mu) * rs * g4.x + e4.x, 0.f);
                float o1 = fmaxf((v[1] - mu) * rs * g4.y + e4.y, 0.f);
                float o2 = fmaxf((v[2] - mu) * rs * g4.z + e4.z, 0.f);
                float o3 = fmaxf((v[3] - mu) * rs * g4.w + e4.w, 0.f);
                if (vm) {
                    uint2 ob;
                    ob.x = cvt_pk_bf16(o0, o1);
                    ob.y = cvt_pk_bf16(o2, o3);
                    *(uint2*)(obrow + nt * 16) = ob;
                }
            }
        } else {
            const ushort_t* grow = orig_bf + (size_t)m * HDIM + nb;
            float t1 = 0.f, t2 = 0.f;
#pragma unroll
            for (int nt = 0; nt < 4; ++nt) {
                const float4 g4 = *(const float4*)(g1v + nb + nt * 16);
                const float4 e4 = *(const float4*)(b1v + nb + nt * 16);
                float4 o4 = {0.f, 0.f, 0.f, 0.f};
                if (vm) {
                    uint2 gb = *(const uint2*)(grow + nt * 16);
                    o4.x = bf_lo(gb.x); o4.y = bf_hi(gb.x);
                    o4.z = bf_lo(gb.y); o4.w = bf_hi(gb.y);
                }
                f32x4 v = acc[rt][nt];
                f32x4 u;
                u[0] = fmaxf((v[0] - mu) * rs * g4.x + e4.x, 0.f) + o4.x;
                u[1] = fmaxf((v[1] - mu) * rs * g4.y + e4.y, 0.f) + o4.y;
                u[2] = fmaxf((v[2] - mu) * rs * g4.z + e4.z, 0.f) + o4.z;
                u[3] = fmaxf((v[3] - mu) * rs * g4.w + e4.w, 0.f) + o4.w;
                acc[rt][nt] = u;
                t1 += u[0] + u[1] + u[2] + u[3];
                t2 += u[0] * u[0] + u[1] * u[1] + u[2] * u[2] + u[3] * u[3];
            }
            t1 += __shfl_xor(t1, 16); t1 += __shfl_xor(t1, 32);
            t2 += __shfl_xor(t2, 16); t2 += __shfl_xor(t2, 32);
            if (l < 16) { ps3[rt * 16 + c][wv] = t1; ps4[rt * 16 + c][wv] = t2; }
        }
    }
    if constexpr (MODE == 1) {
        __syncthreads();
#pragma unroll
        for (int rt = 0; rt < 4; ++rt) {
            const int m = m0 + rt * 16 + c;
            const bool vm = m < M;
            float4 p1 = *(const float4*)ps3[rt * 16 + c];
            float4 p2 = *(const float4*)ps4[rt * 16 + c];
            float s1 = p1.x + p1.y + p1.z + p1.w;
            float s2 = p2.x + p2.y + p2.z + p2.w;
            float mu2 = s1 * (1.f / HDIM);
            float var2 = s2 * (1.f / HDIM) - mu2 * mu2;
            float rs2 = rsqrtf(var2 + 1e-5f);
            float* orow = out + (size_t)m * HDIM + nb;
#pragma unroll
            for (int nt = 0; nt < 4; ++nt) {
                const float4 g4 = *(const float4*)(g2v + nb + nt * 16);
                const float4 e4 = *(const float4*)(b2v + nb + nt * 16);
                f32x4 u = acc[rt][nt];
                float4 o;
                o.x = (u[0] - mu2) * rs2 * g4.x + e4.x;
                o.y = (u[1] - mu2) * rs2 * g4.y + e4.y;
                o.z = (u[2] - mu2) * rs2 * g4.z + e4.z;
                o.w = (u[3] - mu2) * rs2 * g4.w + e4.w;
                if (vm) *(float4*)(orow + nt * 16) = o;
            }
        }
    }
}

// ---------------- launch ----------------

extern "C" void kernel_launch(void* const* d_in, const int* in_sizes, int n_in,
                              void* d_out, int out_size, void* d_ws, size_t ws_size,
                              hipStream_t stream) {
    const float* x    = (const float*)d_in[0];
    const int*   eib  = (const int*)d_in[1];
    const float* eab  = (const float*)d_in[2];
    const int*   eit  = (const int*)d_in[3];
    const float* eat  = (const float*)d_in[4];
    const float* Wb   = (const float*)d_in[5];
    const float* bb   = (const float*)d_in[6];
    const float* Wt   = (const float*)d_in[7];
    const float* bt   = (const float*)d_in[8];
    const float* W1   = (const float*)d_in[9];
    const float* b1   = (const float*)d_in[10];
    const float* g1   = (const float*)d_in[11];
    const float* be1  = (const float*)d_in[12];
    const float* W2   = (const float*)d_in[13];
    const float* b2   = (const float*)d_in[14];
    const float* gs   = (const float*)d_in[15];
    const float* bs   = (const float*)d_in[16];
    const float* gt   = (const float*)d_in[17];
    const float* btn  = (const float*)d_in[18];

    const int Nn = in_sizes[0] / HDIM;     // 50000
    const int Ne = in_sizes[2];            // 800000

    const int* src_b = eib;  const int* dst_b = eib + Ne;
    const int* src_t = eit;  const int* dst_t = eit + Ne;

    char* w = (char*)d_ws;
    ushort_t* aggb = (ushort_t*)w; w += (size_t)Nn * HDIM * 2;
    ushort_t* xb   = (ushort_t*)w; w += (size_t)Nn * HDIM * 2;
    ushort_t* x1b  = (ushort_t*)w; w += (size_t)Nn * HDIM * 2;
    float*    wtmp = (float*)w;    w += (size_t)Ne * 4;
    float*    dinv = (float*)w;    w += (size_t)Nn * 4;
    int*      cnt  = (int*)w;      w += (size_t)Nn * 4;
    int*      rptr = (int*)w;      w += (size_t)(Nn + 4) * 4;
    int*      cur  = (int*)w;      w += (size_t)Nn * 4;
    uint2*    edata = (uint2*)w;   w += (size_t)Ne * 8;
    int*      bsum = (int*)w;      w += (size_t)256 * 4;
    ushort_t* W1p  = (ushort_t*)w; w += (size_t)256 * KAP * 2;
    ushort_t* Wbp  = (ushort_t*)w; w += (size_t)256 * 256 * 2;
    ushort_t* Wtp  = (ushort_t*)w; w += (size_t)256 * 256 * 2;

    float* out = (float*)d_out;
    dim3 b256(256);
    dim3 gN((Nn + 255) / 256), gE((Ne + 255) / 256);
    const int nbScan = (Nn + 255) / 256;
    dim3 gAgg((Nn + 3) / 4);
    dim3 gGemmN((Nn + 63) / 64);
    const int ntiles = (Ne + 63) / 64;
    dim3 gMlp(512);
    const int n4 = Nn * HDIM / 4;
    dim3 gCvt((n4 + 255) / 256);
    const int nPrep = 256 * KAP + 2 * 256 * 256;

    // ---- weight prep (bf16, fused) + x mirror ----
    prep_all_w_kernel<<<dim3((nPrep + 255) / 256), b256, 0, stream>>>(W1, W1p, Wb, Wbp, Wt, Wtp);
    f32_to_bf16_kernel<<<gCvt, b256, 0, stream>>>(x, xb, n4);

    // ---- stage A: BOLD GCN ----
    hipMemsetAsync(cnt, 0, (size_t)Nn * 4, stream);
    hist_cnt_kernel<<<gE, b256, 0, stream>>>(dst_b, cnt, Ne);
    scan_a_kernel<<<dim3(nbScan), b256, 0, stream>>>(cnt, bsum, Nn);
    scan_b_kernel<<<dim3(1), b256, 0, stream>>>(bsum, nbScan);
    scan_c_kernel<<<dim3(nbScan), b256, 0, stream>>>(cnt, bsum, rptr, cur, Nn);
    fill_kernel<<<gE, b256, 0, stream>>>(src_b, dst_b, eab, cur, edata, Ne);
    deg_kernel<<<gN, b256, 0, stream>>>(edata, rptr, dinv, Nn);
    agg_kernel<<<gAgg, b256, 0, stream>>>(xb, rptr, edata, dinv, aggb, Nn);
    gemm_node_kernel<0><<<gGemmN, b256, 0, stream>>>(
        aggb, Wbp, bb, xb, nullptr, gs, bs, nullptr, nullptr, nullptr, x1b, Nn);

    // ---- temporal edge-weight MLP (persistent, dbuf, R13 config) ----
    mlp_mfma_kernel<<<gMlp, b256, 0, stream>>>(
        eat, W1p, b1, g1, be1, W2, b2, wtmp, Ne, ntiles);

    // ---- stage B: temporal GCN + final LN ----
    hipMemsetAsync(cnt, 0, (size_t)Nn * 4, stream);
    hist_cnt_kernel<<<gE, b256, 0, stream>>>(dst_t, cnt, Ne);
    scan_a_kernel<<<dim3(nbScan), b256, 0, stream>>>(cnt, bsum, Nn);
    scan_b_kernel<<<dim3(1), b256, 0, stream>>>(bsum, nbScan);
    scan_c_kernel<<<dim3(nbScan), b256, 0, stream>>>(cnt, bsum, rptr, cur, Nn);
    fill_kernel<<<gE, b256, 0, stream>>>(src_t, dst_t, wtmp, cur, edata, Ne);
    deg_kernel<<<gN, b256, 0, stream>>>(edata, rptr, dinv, Nn);
    agg_kernel<<<gAgg, b256, 0, stream>>>(x1b, rptr, edata, dinv, aggb, Nn);
    gemm_node_kernel<1><<<gGemmN, b256, 0, stream>>>(
        aggb, Wtp, bt, x1b, xb, gt, btn, gs, bs, out, nullptr, Nn);
}

// Round 16
// 775.169 us; speedup vs baseline: 2.0271x; 1.0045x over previous
//
#include <hip/hip_runtime.h>

#define HDIM 256
#define KA 107
#define KAP 128

typedef short bf16x8 __attribute__((ext_vector_type(8)));
typedef float f32x4 __attribute__((ext_vector_type(4)));
typedef unsigned short ushort_t;

__device__ inline unsigned short f2bf(float f) {
    union { float f; unsigned u; } v; v.f = f;
    unsigned r = v.u + 0x7fff + ((v.u >> 16) & 1);
    return (unsigned short)(r >> 16);
}

__device__ inline unsigned cvt_pk_bf16(float a, float b) {
    unsigned r;
    asm("v_cvt_pk_bf16_f32 %0, %1, %2" : "=v"(r) : "v"(a), "v"(b));
    return r;   // low16 = bf16(a), high16 = bf16(b)
}

__device__ inline float bf_lo(unsigned u) { union { unsigned v; float f; } x; x.v = u << 16; return x.f; }
__device__ inline float bf_hi(unsigned u) { union { unsigned v; float f; } x; x.v = u & 0xffff0000u; return x.f; }

__device__ inline float4 guarded_load4(const float* p, size_t off, size_t tot) {
    if (off + 4 <= tot) return *(const float4*)(p + off);
    float4 r = {0.f, 0.f, 0.f, 0.f};
    float* rr = (float*)&r;
    for (int e = 0; e < 4; ++e) if (off + e < tot) rr[e] = p[off + e];
    return r;
}

// ---------------- small kernels ----------------

// count histogram only (1 atomic per edge)
__global__ void hist_cnt_kernel(const int* __restrict__ dst, int* cnt, int ne) {
    int e = blockIdx.x * 256 + threadIdx.x;
    if (e < ne) atomicAdd(&cnt[dst[e]], 1);
}

// f32 -> bf16 mirror (float4 -> uint2)
__global__ void f32_to_bf16_kernel(const float* __restrict__ in, ushort_t* __restrict__ out, int n4) {
    int i = blockIdx.x * 256 + threadIdx.x;
    if (i < n4) {
        float4 v = ((const float4*)in)[i];
        uint2 o;
        o.x = cvt_pk_bf16(v.x, v.y);
        o.y = cvt_pk_bf16(v.z, v.w);
        ((uint2*)out)[i] = o;
    }
}

// fused bf16 prep for W1 (107->128 pad), Wb (256), Wt (256)
__global__ void prep_all_w_kernel(const float* __restrict__ W1, ushort_t* __restrict__ W1p,
                                  const float* __restrict__ Wb, ushort_t* __restrict__ Wbp,
                                  const float* __restrict__ Wt, ushort_t* __restrict__ Wtp) {
    const int n1 = 256 * KAP, n2 = 256 * 256;
    int i = blockIdx.x * 256 + threadIdx.x;
    if (i < n1) {
        int n = i >> 7, k = i & (KAP - 1);
        W1p[i] = (k < KA) ? f2bf(W1[n * KA + k]) : (ushort_t)0;
    } else if (i < n1 + n2) {
        int j = i - n1;
        Wbp[j] = f2bf(Wb[j]);
    } else if (i < n1 + 2 * n2) {
        int j = i - n1 - n2;
        Wtp[j] = f2bf(Wt[j]);
    }
}

// ---------------- multi-block scan (3 phases) ----------------
// phase A: per-block sum of cnt[256] -> bsum[bid]
__global__ __launch_bounds__(256) void scan_a_kernel(const int* __restrict__ cnt,
                                                     int* __restrict__ bsum, int n) {
    const int tid = threadIdx.x;
    const int i = blockIdx.x * 256 + tid;
    int v = (i < n) ? cnt[i] : 0;
    int s = v;
#pragma unroll
    for (int d = 1; d < 64; d <<= 1) s += __shfl_xor(s, d);
    __shared__ int ws[4];
    if ((tid & 63) == 0) ws[tid >> 6] = s;
    __syncthreads();
    if (tid == 0) bsum[blockIdx.x] = ws[0] + ws[1] + ws[2] + ws[3];
}

// phase B: single small block scans nb block sums in place -> exclusive offsets
__global__ __launch_bounds__(256) void scan_b_kernel(int* __restrict__ bsum, int nb) {
    const int tid = threadIdx.x;
    int v = (tid < nb) ? bsum[tid] : 0;
    const int lane = tid & 63, wid = tid >> 6;
    int incl = v;
#pragma unroll
    for (int d = 1; d < 64; d <<= 1) { int m = __shfl_up(incl, d); if (lane >= d) incl += m; }
    __shared__ int ws[4];
    if (lane == 63) ws[wid] = incl;
    __syncthreads();
    if (tid < 4) {
        int wv = ws[tid];
        int iv = wv;
#pragma unroll
        for (int d = 1; d < 4; d <<= 1) { int m = __shfl_up(iv, d, 4); if (tid >= d) iv += m; }
        ws[tid] = iv - wv;
    }
    __syncthreads();
    if (tid < nb) bsum[tid] = (incl - v) + ws[wid];
}

// phase C: in-block exclusive scan + block offset -> rptr, cur; rptr[n] at tail
__global__ __launch_bounds__(256) void scan_c_kernel(const int* __restrict__ cnt,
                                                     const int* __restrict__ bsum,
                                                     int* __restrict__ rptr,
                                                     int* __restrict__ cur, int n) {
    const int tid = threadIdx.x;
    const int i = blockIdx.x * 256 + tid;
    int v = (i < n) ? cnt[i] : 0;
    const int lane = tid & 63, wid = tid >> 6;
    int incl = v;
#pragma unroll
    for (int d = 1; d < 64; d <<= 1) { int m = __shfl_up(incl, d); if (lane >= d) incl += m; }
    __shared__ int ws[4];
    if (lane == 63) ws[wid] = incl;
    __syncthreads();
    if (tid < 4) {
        int wv = ws[tid];
        int iv = wv;
#pragma unroll
        for (int d = 1; d < 4; d <<= 1) { int m = __shfl_up(iv, d, 4); if (tid >= d) iv += m; }
        ws[tid] = iv - wv;
    }
    __syncthreads();
    const int excl = (incl - v) + ws[wid] + bsum[blockIdx.x];
    if (i < n) { rptr[i] = excl; cur[i] = excl; }
    if (i == n - 1) rptr[n] = excl + v;
}

// bucket edges by dst; store raw (src, w) — NO dinv dependency
__global__ void fill_kernel(const int* __restrict__ src, const int* __restrict__ dst,
                            const float* __restrict__ w,
                            int* cur, uint2* __restrict__ edata, int ne) {
    int e = blockIdx.x * 256 + threadIdx.x;
    if (e < ne) {
        int d = dst[e];
        int pos = atomicAdd(&cur[d], 1);
        uint2 ed;
        ed.x = (unsigned)src[e];
        ed.y = __float_as_uint(w[e]);
        edata[pos] = ed;
    }
}

// per-node weighted degree from sorted edata (coalesced, no atomics) -> dinv
__global__ void deg_kernel(const uint2* __restrict__ edata, const int* __restrict__ rptr,
                           float* __restrict__ dinv, int n) {
    int v = blockIdx.x * 256 + threadIdx.x;
    if (v < n) {
        const int b = rptr[v], e = rptr[v + 1];
        float s = 1.0f;   // self-loop weight
        for (int i = b; i < e; ++i) s += __uint_as_float(edata[i].y);
        dinv[v] = s > 0.f ? rsqrtf(s) : 0.f;
    }
}

// one wave per dst node; 8 independent edge chains; norm computed at prefetch
__global__ __launch_bounds__(256) void agg_kernel(const ushort_t* __restrict__ Xb,
                                                  const int* __restrict__ rptr,
                                                  const uint2* __restrict__ edata,
                                                  const float* __restrict__ dinv,
                                                  ushort_t* __restrict__ out, int n) {
    const int v = blockIdx.x * 4 + (threadIdx.x >> 6);
    if (v >= n) return;
    const int lane = threadIdx.x & 63;
    const float dv = dinv[v];
    const uint2 xv = *(const uint2*)(Xb + (size_t)v * HDIM + lane * 4);
    const float dv2 = dv * dv;
    float a0[8], a1[8], a2[8], a3[8];
#pragma unroll
    for (int c = 0; c < 8; ++c) { a0[c] = 0.f; a1[c] = 0.f; a2[c] = 0.f; a3[c] = 0.f; }
    a0[0] = dv2 * bf_lo(xv.x); a1[0] = dv2 * bf_hi(xv.x);
    a2[0] = dv2 * bf_lo(xv.y); a3[0] = dv2 * bf_hi(xv.y);

    const int b = rptr[v];
    const int total = rptr[v + 1] - b;
    uint2 pv[8]; float pn[8];
#pragma unroll
    for (int c = 0; c < 8; ++c) {
        if (c < total) {
            uint2 ed = edata[b + c];
            pn[c] = dinv[ed.x] * __uint_as_float(ed.y) * dv;
            pv[c] = *(const uint2*)(Xb + (size_t)ed.x * HDIM + lane * 4);
        }
    }
    for (int base = 0; base < total; base += 8) {
#pragma unroll
        for (int c = 0; c < 8; ++c) {
            if (base + c < total) {
                uint2 cv = pv[c]; float cn = pn[c];
                int nx = base + 8 + c;
                if (nx < total) {
                    uint2 ed = edata[b + nx];
                    pn[c] = dinv[ed.x] * __uint_as_float(ed.y) * dv;
                    pv[c] = *(const uint2*)(Xb + (size_t)ed.x * HDIM + lane * 4);
                }
                a0[c] = fmaf(cn, bf_lo(cv.x), a0[c]);
                a1[c] = fmaf(cn, bf_hi(cv.x), a1[c]);
                a2[c] = fmaf(cn, bf_lo(cv.y), a2[c]);
                a3[c] = fmaf(cn, bf_hi(cv.y), a3[c]);
            }
        }
    }
    float r0 = ((a0[0] + a0[1]) + (a0[2] + a0[3])) + ((a0[4] + a0[5]) + (a0[6] + a0[7]));
    float r1 = ((a1[0] + a1[1]) + (a1[2] + a1[3])) + ((a1[4] + a1[5]) + (a1[6] + a1[7]));
    float r2 = ((a2[0] + a2[1]) + (a2[2] + a2[3])) + ((a2[4] + a2[5]) + (a2[6] + a2[7]));
    float r3 = ((a3[0] + a3[1]) + (a3[2] + a3[3])) + ((a3[4] + a3[5]) + (a3[6] + a3[7]));
    uint2 o;
    o.x = cvt_pk_bf16(r0, r1);
    o.y = cvt_pk_bf16(r2, r3);
    *(uint2*)(out + (size_t)v * HDIM + lane * 4) = o;
}

// ---------------- edge MLP: persistent, dbuf LDS, f32 staging (late cvt), PARTIAL W hoist ----------------
// R13 structure; wreg hoists only nt<2 (32 VGPR), nt>=2 fragments stream from L1 in-loop.
// Target: ~155-165 VGPR -> 3 waves/SIMD (vs 184 -> 2).
__global__ __launch_bounds__(256) void mlp_mfma_kernel(
    const float* __restrict__ A,            // [M][107] f32
    const ushort_t* __restrict__ Wp,        // [256][128] bf16, zero-padded k>=107
    const float* __restrict__ b1v, const float* __restrict__ g1v,
    const float* __restrict__ be1v, const float* __restrict__ W2,
    const float* __restrict__ b2s, float* __restrict__ out,
    int M, int ntiles) {
    __shared__ ushort_t As[2][64][136];
    __shared__ float ps1[64][4], ps2[64][4], pd[64][4];
    const int tid = threadIdx.x;
    const int l = tid & 63, wv = tid >> 6, g = l >> 4, c = l & 15;
    const float b2sc = b2s[0];
    const size_t tot = (size_t)M * KA;

    // one-time zero of k in [112,128) for BOTH buffers (staging never writes there;
    // k in [107,112) gets finite garbage each tile, killed by W zero-pad)
    for (int z = tid; z < 2 * 64 * 16; z += 256) {
        int buf = z >> 10;
        int rem = z & 1023;
        As[buf][rem >> 4][112 + (rem & 15)] = 0;
    }

    // partial hoist: wreg[ks][nt] for nt<2 only (32 VGPR)
    const ushort_t* wb = Wp + (size_t)(wv * 64 + c) * KAP + g * 8;
    bf16x8 wreg[4][2];
#pragma unroll
    for (int ks = 0; ks < 4; ++ks)
#pragma unroll
        for (int nt = 0; nt < 2; ++nt)
            wreg[ks][nt] = *(const bf16x8*)(wb + nt * 16 * KAP + ks * 32);

    // staging role: 4 threads per row; thread (srow=tid>>2, sj=tid&3) covers k = sj*4 + i*16, i<7
    const int srow = tid >> 2, sj = tid & 3;
    float4 sreg[7];

    // ---- prologue: stage tile t0 into buf 0 ----
    const int t0 = blockIdx.x;
    if (t0 < ntiles) {
        const size_t roff = (size_t)(t0 * 64 + srow) * KA + sj * 4;
#pragma unroll
        for (int i = 0; i < 7; ++i) sreg[i] = guarded_load4(A, roff + i * 16, tot);
#pragma unroll
        for (int i = 0; i < 7; ++i) {
            uint2 o;
            o.x = cvt_pk_bf16(sreg[i].x, sreg[i].y);
            o.y = cvt_pk_bf16(sreg[i].z, sreg[i].w);
            *(uint2*)&As[0][srow][sj * 4 + i * 16] = o;
        }
    }
    __syncthreads();

    int cur = 0;
    for (int t = t0; t < ntiles; t += gridDim.x) {
        const int tn = t + gridDim.x;
        const bool have_next = tn < ntiles;
        // (A) issue next tile's loads early (f32, consumed only at (E))
        if (have_next) {
            const size_t roff = (size_t)(tn * 64 + srow) * KA + sj * 4;
#pragma unroll
            for (int i = 0; i < 7; ++i) sreg[i] = guarded_load4(A, roff + i * 16, tot);
        }

        // (B) MFMA on As[cur]; nt<2 W from registers, nt>=2 from L1
        f32x4 acc[4][4];
#pragma unroll
        for (int rt = 0; rt < 4; ++rt)
#pragma unroll
            for (int nt = 0; nt < 4; ++nt) acc[rt][nt] = (f32x4){0.f, 0.f, 0.f, 0.f};
        __builtin_amdgcn_s_setprio(1);
#pragma unroll
        for (int ks = 0; ks < 4; ++ks) {
            bf16x8 af[4];
#pragma unroll
            for (int rt = 0; rt < 4; ++rt)
                af[rt] = *(const bf16x8*)&As[cur][rt * 16 + c][ks * 32 + g * 8];
#pragma unroll
            for (int nt = 0; nt < 4; ++nt) {
                bf16x8 wfr = (nt < 2) ? wreg[ks][nt]
                                      : *(const bf16x8*)(wb + nt * 16 * KAP + ks * 32);
#pragma unroll
                for (int rt = 0; rt < 4; ++rt)
                    acc[rt][nt] = __builtin_amdgcn_mfma_f32_16x16x32_bf16(wfr, af[rt], acc[rt][nt], 0, 0, 0);
            }
        }
        __builtin_amdgcn_s_setprio(0);

        const int nb = wv * 64 + (g << 2);
        const int m0 = t * 64;
        // (C) pass 1: bias + row sums
#pragma unroll
        for (int rt = 0; rt < 4; ++rt) {
            float s1 = 0.f, s2 = 0.f;
#pragma unroll
            for (int nt = 0; nt < 4; ++nt) {
                const float4 b4 = *(const float4*)(b1v + nb + nt * 16);
                f32x4 v = acc[rt][nt];
                v[0] += b4.x; v[1] += b4.y; v[2] += b4.z; v[3] += b4.w;
                acc[rt][nt] = v;
                s1 += v[0] + v[1] + v[2] + v[3];
                s2 += v[0] * v[0] + v[1] * v[1] + v[2] * v[2] + v[3] * v[3];
            }
            s1 += __shfl_xor(s1, 16); s1 += __shfl_xor(s1, 32);
            s2 += __shfl_xor(s2, 16); s2 += __shfl_xor(s2, 32);
            if (l < 16) { ps1[rt * 16 + c][wv] = s1; ps2[rt * 16 + c][wv] = s2; }
        }
        __syncthreads();   // barrier 1: ps published
        // (D) pass 2: LN + relu + dot(W2) -> pd
#pragma unroll
        for (int rt = 0; rt < 4; ++rt) {
            float4 p1 = *(const float4*)ps1[rt * 16 + c];
            float4 p2 = *(const float4*)ps2[rt * 16 + c];
            float s1 = p1.x + p1.y + p1.z + p1.w;
            float s2 = p2.x + p2.y + p2.z + p2.w;
            float mu = s1 * (1.f / HDIM);
            float var = s2 * (1.f / HDIM) - mu * mu;
            float rs = rsqrtf(var + 1e-5f);
            float dacc = 0.f;
#pragma unroll
            for (int nt = 0; nt < 4; ++nt) {
                const float4 g4 = *(const float4*)(g1v + nb + nt * 16);
                const float4 e4 = *(const float4*)(be1v + nb + nt * 16);
                const float4 w4 = *(const float4*)(W2 + nb + nt * 16);
                f32x4 v = acc[rt][nt];
                float y0 = fmaxf((v[0] - mu) * rs * g4.x + e4.x, 0.f);
                float y1 = fmaxf((v[1] - mu) * rs * g4.y + e4.y, 0.f);
                float y2 = fmaxf((v[2] - mu) * rs * g4.z + e4.z, 0.f);
                float y3 = fmaxf((v[3] - mu) * rs * g4.w + e4.w, 0.f);
                dacc = fmaf(y0, w4.x, dacc); dacc = fmaf(y1, w4.y, dacc);
                dacc = fmaf(y2, w4.z, dacc); dacc = fmaf(y3, w4.w, dacc);
            }
            dacc += __shfl_xor(dacc, 16); dacc += __shfl_xor(dacc, 32);
            if (l < 16) pd[rt * 16 + c][wv] = dacc;
        }
        // (E) cvt + write next buffer (vmcnt wait lands HERE, after MFMA+epilogue)
        if (have_next) {
#pragma unroll
            for (int i = 0; i < 7; ++i) {
                uint2 o;
                o.x = cvt_pk_bf16(sreg[i].x, sreg[i].y);
                o.y = cvt_pk_bf16(sreg[i].z, sreg[i].w);
                *(uint2*)&As[cur ^ 1][srow][sj * 4 + i * 16] = o;
            }
        }
        __syncthreads();   // barrier 2: pd published + As[cur^1] complete
        // (F) out store for tile t
        if (tid < 64) {
            float4 p = *(const float4*)pd[tid];
            int gr = m0 + tid;
            if (gr < M) out[gr] = p.x + p.y + p.z + p.w + b2sc;
        }
        cur ^= 1;
    }
}

// ---------------- node GEMM: bf16 MFMA, C^T epilogue, fused LN(s), bf16 residuals ----------------
template <int MODE>
__global__ __launch_bounds__(256) void gemm_node_kernel(
    const ushort_t* __restrict__ A,
    const ushort_t* __restrict__ Wp,
    const float* __restrict__ bias,
    const ushort_t* __restrict__ res_bf,
    const ushort_t* __restrict__ orig_bf,
    const float* __restrict__ g1v, const float* __restrict__ b1v,
    const float* __restrict__ g2v, const float* __restrict__ b2v,
    float* __restrict__ out, ushort_t* __restrict__ out_bf, int M) {
    __shared__ ushort_t As[64][264];
    __shared__ float ps1[64][4], ps2[64][4], ps3[64][4], ps4[64][4];
    const int tid = threadIdx.x;
    const int m0 = blockIdx.x * 64;
    const int l = tid & 63, wv = tid >> 6, g = l >> 4, c = l & 15;

    {
        const int r = tid >> 2, j = tid & 3;
        const ushort_t* gsrc = A + (size_t)(m0 + r) * HDIM;
        const bool ok = (m0 + r) < M;
#pragma unroll
        for (int i = 0; i < 8; ++i) {
            const int ci = i * 4 + j;
            bf16x8 v = (bf16x8){0,0,0,0,0,0,0,0};
            if (ok) v = *(const bf16x8*)(gsrc + ci * 8);
            *(bf16x8*)&As[r][ci * 8] = v;
        }
    }
    __syncthreads();

    f32x4 acc[4][4];
#pragma unroll
    for (int rt = 0; rt < 4; ++rt)
#pragma unroll
        for (int nt = 0; nt < 4; ++nt) acc[rt][nt] = (f32x4){0.f, 0.f, 0.f, 0.f};

    const ushort_t* wb = Wp + (size_t)(wv * 64 + c) * HDIM + g * 8;
    __builtin_amdgcn_s_setprio(1);
#pragma unroll
    for (int ks = 0; ks < 8; ++ks) {
        bf16x8 af[4];
#pragma unroll
        for (int rt = 0; rt < 4; ++rt)
            af[rt] = *(const bf16x8*)&As[rt * 16 + c][ks * 32 + g * 8];
#pragma unroll
        for (int nt = 0; nt < 4; ++nt) {
            bf16x8 bfr = *(const bf16x8*)(wb + nt * 16 * HDIM + ks * 32);
#pragma unroll
            for (int rt = 0; rt < 4; ++rt)
                acc[rt][nt] = __builtin_amdgcn_mfma_f32_16x16x32_bf16(bfr, af[rt], acc[rt][nt], 0, 0, 0);
        }
    }
    __builtin_amdgcn_s_setprio(0);

    const int nb = wv * 64 + (g << 2);
#pragma unroll
    for (int rt = 0; rt < 4; ++rt) {
        const int m = m0 + rt * 16 + c;
        const bool vm = m < M;
        const ushort_t* rrow = res_bf + (size_t)m * HDIM + nb;
        float s1 = 0.f, s2 = 0.f;
#pragma unroll
        for (int nt = 0; nt < 4; ++nt) {
            const float4 b4 = *(const float4*)(bias + nb + nt * 16);
            float4 r4 = {0.f, 0.f, 0.f, 0.f};
            if (vm) {
                uint2 rb = *(const uint2*)(rrow + nt * 16);
                r4.x = bf_lo(rb.x); r4.y = bf_hi(rb.x);
                r4.z = bf_lo(rb.y); r4.w = bf_hi(rb.y);
            }
            f32x4 v = acc[rt][nt];
            v[0] += b4.x + r4.x; v[1] += b4.y + r4.y;
            v[2] += b4.z + r4.z; v[3] += b4.w + r4.w;
            acc[rt][nt] = v;
            s1 += v[0] + v[1] + v[2] + v[3];
            s2 += v[0] * v[0] + v[1] * v[1] + v[2] * v[2] + v[3] * v[3];
        }
        s1 += __shfl_xor(s1, 16); s1 += __shfl_xor(s1, 32);
        s2 += __shfl_xor(s2, 16); s2 += __shfl_xor(s2, 32);
        if (l < 16) { ps1[rt * 16 + c][wv] = s1; ps2[rt * 16 + c][wv] = s2; }
    }
    __syncthreads();
#pragma unroll
    for (int rt = 0; rt < 4; ++rt) {
        const int m = m0 + rt * 16 + c;
        const bool vm = m < M;
        float4 p1 = *(const float4*)ps1[rt * 16 + c];
        float4 p2 = *(const float4*)ps2[rt * 16 + c];
        float s1 = p1.x + p1.y + p1.z + p1.w;
        float s2 = p2.x + p2.y + p2.z + p2.w;
        float mu = s1 * (1.f / HDIM);
        float var = s2 * (1.f / HDIM) - mu * mu;
        float rs = rsqrtf(var + 1e-5f);
        if constexpr (MODE == 0) {
            ushort_t* obrow = out_bf + (size_t)m * HDIM + nb;
#pragma unroll
            for (int nt = 0; nt < 4; ++nt) {
                const float4 g4 = *(const float4*)(g1v + nb + nt * 16);
                const float4 e4 = *(const float4*)(b1v + nb + nt * 16);
                f32x4 v = acc[rt][nt];
                float o0 = fmaxf((v[0] - mu) * rs * g4.x + e4.x, 0.f);
                float o1 = fmaxf((v[1] - mu) * rs * g4.y + e4.y, 0.f);
                float o2 = fmaxf((v[2] - mu) * rs * g4.z + e4.z, 0.f);
                float o3 = fmaxf((v[3] - mu) * rs * g4.w + e4.w, 0.f);
                if (vm) {
                    uint2 ob;
                    ob.x = cvt_pk_bf16(o0, o1);
                    ob.y = cvt_pk_bf16(o2, o3);
                    *(uint2*)(obrow + nt * 16) = ob;
                }
            }
        } else {
            const ushort_t* grow = orig_bf + (size_t)m * HDIM + nb;
            float t1 = 0.f, t2 = 0.f;
#pragma unroll
            for (int nt = 0; nt < 4; ++nt) {
                const float4 g4 = *(const float4*)(g1v + nb + nt * 16);
                const float4 e4 = *(const float4*)(b1v + nb + nt * 16);
                float4 o4 = {0.f, 0.f, 0.f, 0.f};
                if (vm) {
                    uint2 gb = *(const uint2*)(grow + nt * 16);
                    o4.x = bf_lo(gb.x); o4.y = bf_hi(gb.x);
                    o4.z = bf_lo(gb.y); o4.w = bf_hi(gb.y);
                }
                f32x4 v = acc[rt][nt];
                f32x4 u;
                u[0] = fmaxf((v[0] - mu) * rs * g4.x + e4.x, 0.f) + o4.x;
                u[1] = fmaxf((v[1] - mu) * rs * g4.y + e4.y, 0.f) + o4.y;
                u[2] = fmaxf((v[2] - mu) * rs * g4.z + e4.z, 0.f) + o4.z;
                u[3] = fmaxf((v[3] - mu) * rs * g4.w + e4.w, 0.f) + o4.w;
                acc[rt][nt] = u;
                t1 += u[0] + u[1] + u[2] + u[3];
                t2 += u[0] * u[0] + u[1] * u[1] + u[2] * u[2] + u[3] * u[3];
            }
            t1 += __shfl_xor(t1, 16); t1 += __shfl_xor(t1, 32);
            t2 += __shfl_xor(t2, 16); t2 += __shfl_xor(t2, 32);
            if (l < 16) { ps3[rt * 16 + c][wv] = t1; ps4[rt * 16 + c][wv] = t2; }
        }
    }
    if constexpr (MODE == 1) {
        __syncthreads();
#pragma unroll
        for (int rt = 0; rt < 4; ++rt) {
            const int m = m0 + rt * 16 + c;
            const bool vm = m < M;
            float4 p1 = *(const float4*)ps3[rt * 16 + c];
            float4 p2 = *(const float4*)ps4[rt * 16 + c];
            float s1 = p1.x + p1.y + p1.z + p1.w;
            float s2 = p2.x + p2.y + p2.z + p2.w;
            float mu2 = s1 * (1.f / HDIM);
            float var2 = s2 * (1.f / HDIM) - mu2 * mu2;
            float rs2 = rsqrtf(var2 + 1e-5f);
            float* orow = out + (size_t)m * HDIM + nb;
#pragma unroll
            for (int nt = 0; nt < 4; ++nt) {
                const float4 g4 = *(const float4*)(g2v + nb + nt * 16);
                const float4 e4 = *(const float4*)(b2v + nb + nt * 16);
                f32x4 u = acc[rt][nt];
                float4 o;
                o.x = (u[0] - mu2) * rs2 * g4.x + e4.x;
                o.y = (u[1] - mu2) * rs2 * g4.y + e4.y;
                o.z = (u[2] - mu2) * rs2 * g4.z + e4.z;
                o.w = (u[3] - mu2) * rs2 * g4.w + e4.w;
                if (vm) *(float4*)(orow + nt * 16) = o;
            }
        }
    }
}

// ---------------- launch ----------------

extern "C" void kernel_launch(void* const* d_in, const int* in_sizes, int n_in,
                              void* d_out, int out_size, void* d_ws, size_t ws_size,
                              hipStream_t stream) {
    const float* x    = (const float*)d_in[0];
    const int*   eib  = (const int*)d_in[1];
    const float* eab  = (const float*)d_in[2];
    const int*   eit  = (const int*)d_in[3];
    const float* eat  = (const float*)d_in[4];
    const float* Wb   = (const float*)d_in[5];
    const float* bb   = (const float*)d_in[6];
    const float* Wt   = (const float*)d_in[7];
    const float* bt   = (const float*)d_in[8];
    const float* W1   = (const float*)d_in[9];
    const float* b1   = (const float*)d_in[10];
    const float* g1   = (const float*)d_in[11];
    const float* be1  = (const float*)d_in[12];
    const float* W2   = (const float*)d_in[13];
    const float* b2   = (const float*)d_in[14];
    const float* gs   = (const float*)d_in[15];
    const float* bs   = (const float*)d_in[16];
    const float* gt   = (const float*)d_in[17];
    const float* btn  = (const float*)d_in[18];

    const int Nn = in_sizes[0] / HDIM;     // 50000
    const int Ne = in_sizes[2];            // 800000

    const int* src_b = eib;  const int* dst_b = eib + Ne;
    const int* src_t = eit;  const int* dst_t = eit + Ne;

    char* w = (char*)d_ws;
    ushort_t* aggb = (ushort_t*)w; w += (size_t)Nn * HDIM * 2;
    ushort_t* xb   = (ushort_t*)w; w += (size_t)Nn * HDIM * 2;
    ushort_t* x1b  = (ushort_t*)w; w += (size_t)Nn * HDIM * 2;
    float*    wtmp = (float*)w;    w += (size_t)Ne * 4;
    float*    dinv = (float*)w;    w += (size_t)Nn * 4;
    int*      cnt  = (int*)w;      w += (size_t)Nn * 4;
    int*      rptr = (int*)w;      w += (size_t)(Nn + 4) * 4;
    int*      cur  = (int*)w;      w += (size_t)Nn * 4;
    uint2*    edata = (uint2*)w;   w += (size_t)Ne * 8;
    int*      bsum = (int*)w;      w += (size_t)256 * 4;
    ushort_t* W1p  = (ushort_t*)w; w += (size_t)256 * KAP * 2;
    ushort_t* Wbp  = (ushort_t*)w; w += (size_t)256 * 256 * 2;
    ushort_t* Wtp  = (ushort_t*)w; w += (size_t)256 * 256 * 2;

    float* out = (float*)d_out;
    dim3 b256(256);
    dim3 gN((Nn + 255) / 256), gE((Ne + 255) / 256);
    const int nbScan = (Nn + 255) / 256;
    dim3 gAgg((Nn + 3) / 4);
    dim3 gGemmN((Nn + 63) / 64);
    const int ntiles = (Ne + 63) / 64;
    dim3 gMlp(512);
    const int n4 = Nn * HDIM / 4;
    dim3 gCvt((n4 + 255) / 256);
    const int nPrep = 256 * KAP + 2 * 256 * 256;

    // ---- weight prep (bf16, fused) + x mirror ----
    prep_all_w_kernel<<<dim3((nPrep + 255) / 256), b256, 0, stream>>>(W1, W1p, Wb, Wbp, Wt, Wtp);
    f32_to_bf16_kernel<<<gCvt, b256, 0, stream>>>(x, xb, n4);

    // ---- stage A: BOLD GCN ----
    hipMemsetAsync(cnt, 0, (size_t)Nn * 4, stream);
    hist_cnt_kernel<<<gE, b256, 0, stream>>>(dst_b, cnt, Ne);
    scan_a_kernel<<<dim3(nbScan), b256, 0, stream>>>(cnt, bsum, Nn);
    scan_b_kernel<<<dim3(1), b256, 0, stream>>>(bsum, nbScan);
    scan_c_kernel<<<dim3(nbScan), b256, 0, stream>>>(cnt, bsum, rptr, cur, Nn);
    fill_kernel<<<gE, b256, 0, stream>>>(src_b, dst_b, eab, cur, edata, Ne);
    deg_kernel<<<gN, b256, 0, stream>>>(edata, rptr, dinv, Nn);
    agg_kernel<<<gAgg, b256, 0, stream>>>(xb, rptr, edata, dinv, aggb, Nn);
    gemm_node_kernel<0><<<gGemmN, b256, 0, stream>>>(
        aggb, Wbp, bb, xb, nullptr, gs, bs, nullptr, nullptr, nullptr, x1b, Nn);

    // ---- temporal edge-weight MLP (persistent, dbuf, partial hoist) ----
    mlp_mfma_kernel<<<gMlp, b256, 0, stream>>>(
        eat, W1p, b1, g1, be1, W2, b2, wtmp, Ne, ntiles);

    // ---- stage B: temporal GCN + final LN ----
    hipMemsetAsync(cnt, 0, (size_t)Nn * 4, stream);
    hist_cnt_kernel<<<gE, b256, 0, stream>>>(dst_t, cnt, Ne);
    scan_a_kernel<<<dim3(nbScan), b256, 0, stream>>>(cnt, bsum, Nn);
    scan_b_kernel<<<dim3(1), b256, 0, stream>>>(bsum, nbScan);
    scan_c_kernel<<<dim3(nbScan), b256, 0, stream>>>(cnt, bsum, rptr, cur, Nn);
    fill_kernel<<<gE, b256, 0, stream>>>(src_t, dst_t, wtmp, cur, edata, Ne);
    deg_kernel<<<gN, b256, 0, stream>>>(edata, rptr, dinv, Nn);
    agg_kernel<<<gAgg, b256, 0, stream>>>(x1b, rptr, edata, dinv, aggb, Nn);
    gemm_node_kernel<1><<<gGemmN, b256, 0, stream>>>(
        aggb, Wtp, bt, x1b, xb, gt, btn, gs, bs, out, nullptr, Nn);
}

// Round 17
// 762.890 us; speedup vs baseline: 2.0597x; 1.0161x over previous
//
#include <hip/hip_runtime.h>

#define HDIM 256
#define KA 107
#define KAP 128

typedef short bf16x8 __attribute__((ext_vector_type(8)));
typedef float f32x4 __attribute__((ext_vector_type(4)));
typedef unsigned short ushort_t;

__device__ inline unsigned short f2bf(float f) {
    union { float f; unsigned u; } v; v.f = f;
    unsigned r = v.u + 0x7fff + ((v.u >> 16) & 1);
    return (unsigned short)(r >> 16);
}

__device__ inline unsigned cvt_pk_bf16(float a, float b) {
    unsigned r;
    asm("v_cvt_pk_bf16_f32 %0, %1, %2" : "=v"(r) : "v"(a), "v"(b));
    return r;   // low16 = bf16(a), high16 = bf16(b)
}

__device__ inline float bf_lo(unsigned u) { union { unsigned v; float f; } x; x.v = u << 16; return x.f; }
__device__ inline float bf_hi(unsigned u) { union { unsigned v; float f; } x; x.v = u & 0xffff0000u; return x.f; }

__device__ inline float4 guarded_load4(const float* p, size_t off, size_t tot) {
    if (off + 4 <= tot) return *(const float4*)(p + off);
    float4 r = {0.f, 0.f, 0.f, 0.f};
    float* rr = (float*)&r;
    for (int e = 0; e < 4; ++e) if (off + e < tot) rr[e] = p[off + e];
    return r;
}

// ---------------- small kernels ----------------

// count histogram only (1 atomic per edge)
__global__ void hist_cnt_kernel(const int* __restrict__ dst, int* cnt, int ne) {
    int e = blockIdx.x * 256 + threadIdx.x;
    if (e < ne) atomicAdd(&cnt[dst[e]], 1);
}

// f32 -> bf16 mirror (float4 -> uint2)
__global__ void f32_to_bf16_kernel(const float* __restrict__ in, ushort_t* __restrict__ out, int n4) {
    int i = blockIdx.x * 256 + threadIdx.x;
    if (i < n4) {
        float4 v = ((const float4*)in)[i];
        uint2 o;
        o.x = cvt_pk_bf16(v.x, v.y);
        o.y = cvt_pk_bf16(v.z, v.w);
        ((uint2*)out)[i] = o;
    }
}

// fused bf16 prep for W1 (107->128 pad), Wb (256), Wt (256)
__global__ void prep_all_w_kernel(const float* __restrict__ W1, ushort_t* __restrict__ W1p,
                                  const float* __restrict__ Wb, ushort_t* __restrict__ Wbp,
                                  const float* __restrict__ Wt, ushort_t* __restrict__ Wtp) {
    const int n1 = 256 * KAP, n2 = 256 * 256;
    int i = blockIdx.x * 256 + threadIdx.x;
    if (i < n1) {
        int n = i >> 7, k = i & (KAP - 1);
        W1p[i] = (k < KA) ? f2bf(W1[n * KA + k]) : (ushort_t)0;
    } else if (i < n1 + n2) {
        int j = i - n1;
        Wbp[j] = f2bf(Wb[j]);
    } else if (i < n1 + 2 * n2) {
        int j = i - n1 - n2;
        Wtp[j] = f2bf(Wt[j]);
    }
}

// ---------------- multi-block scan (3 phases) ----------------
// phase A: per-block sum of cnt[256] -> bsum[bid]
__global__ __launch_bounds__(256) void scan_a_kernel(const int* __restrict__ cnt,
                                                     int* __restrict__ bsum, int n) {
    const int tid = threadIdx.x;
    const int i = blockIdx.x * 256 + tid;
    int v = (i < n) ? cnt[i] : 0;
    int s = v;
#pragma unroll
    for (int d = 1; d < 64; d <<= 1) s += __shfl_xor(s, d);
    __shared__ int ws[4];
    if ((tid & 63) == 0) ws[tid >> 6] = s;
    __syncthreads();
    if (tid == 0) bsum[blockIdx.x] = ws[0] + ws[1] + ws[2] + ws[3];
}

// phase B: single small block scans nb block sums in place -> exclusive offsets
__global__ __launch_bounds__(256) void scan_b_kernel(int* __restrict__ bsum, int nb) {
    const int tid = threadIdx.x;
    int v = (tid < nb) ? bsum[tid] : 0;
    const int lane = tid & 63, wid = tid >> 6;
    int incl = v;
#pragma unroll
    for (int d = 1; d < 64; d <<= 1) { int m = __shfl_up(incl, d); if (lane >= d) incl += m; }
    __shared__ int ws[4];
    if (lane == 63) ws[wid] = incl;
    __syncthreads();
    if (tid < 4) {
        int wv = ws[tid];
        int iv = wv;
#pragma unroll
        for (int d = 1; d < 4; d <<= 1) { int m = __shfl_up(iv, d, 4); if (tid >= d) iv += m; }
        ws[tid] = iv - wv;
    }
    __syncthreads();
    if (tid < nb) bsum[tid] = (incl - v) + ws[wid];
}

// phase C: in-block exclusive scan + block offset -> rptr, cur; rptr[n] at tail
__global__ __launch_bounds__(256) void scan_c_kernel(const int* __restrict__ cnt,
                                                     const int* __restrict__ bsum,
                                                     int* __restrict__ rptr,
                                                     int* __restrict__ cur, int n) {
    const int tid = threadIdx.x;
    const int i = blockIdx.x * 256 + tid;
    int v = (i < n) ? cnt[i] : 0;
    const int lane = tid & 63, wid = tid >> 6;
    int incl = v;
#pragma unroll
    for (int d = 1; d < 64; d <<= 1) { int m = __shfl_up(incl, d); if (lane >= d) incl += m; }
    __shared__ int ws[4];
    if (lane == 63) ws[wid] = incl;
    __syncthreads();
    if (tid < 4) {
        int wv = ws[tid];
        int iv = wv;
#pragma unroll
        for (int d = 1; d < 4; d <<= 1) { int m = __shfl_up(iv, d, 4); if (tid >= d) iv += m; }
        ws[tid] = iv - wv;
    }
    __syncthreads();
    const int excl = (incl - v) + ws[wid] + bsum[blockIdx.x];
    if (i < n) { rptr[i] = excl; cur[i] = excl; }
    if (i == n - 1) rptr[n] = excl + v;
}

// bucket edges by dst; store raw (src, w) — NO dinv dependency
__global__ void fill_kernel(const int* __restrict__ src, const int* __restrict__ dst,
                            const float* __restrict__ w,
                            int* cur, uint2* __restrict__ edata, int ne) {
    int e = blockIdx.x * 256 + threadIdx.x;
    if (e < ne) {
        int d = dst[e];
        int pos = atomicAdd(&cur[d], 1);
        uint2 ed;
        ed.x = (unsigned)src[e];
        ed.y = __float_as_uint(w[e]);
        edata[pos] = ed;
    }
}

// per-node weighted degree from sorted edata (coalesced, no atomics) -> dinv
__global__ void deg_kernel(const uint2* __restrict__ edata, const int* __restrict__ rptr,
                           float* __restrict__ dinv, int n) {
    int v = blockIdx.x * 256 + threadIdx.x;
    if (v < n) {
        const int b = rptr[v], e = rptr[v + 1];
        float s = 1.0f;   // self-loop weight
        for (int i = b; i < e; ++i) s += __uint_as_float(edata[i].y);
        dinv[v] = s > 0.f ? rsqrtf(s) : 0.f;
    }
}

// TWO waves per dst node (each handles half the edge list with 8 chains),
// LDS combine; 2 nodes per 256-thread block.
__global__ __launch_bounds__(256) void agg_kernel(const ushort_t* __restrict__ Xb,
                                                  const int* __restrict__ rptr,
                                                  const uint2* __restrict__ edata,
                                                  const float* __restrict__ dinv,
                                                  ushort_t* __restrict__ out, int n) {
    __shared__ float4 part[2][64];
    const int pair = threadIdx.x >> 7;          // node slot in block (0,1)
    const int wvh  = (threadIdx.x >> 6) & 1;    // half index within pair
    const int lane = threadIdx.x & 63;
    const int v = blockIdx.x * 2 + pair;
    const bool valid = v < n;

    const float dv = valid ? dinv[v] : 0.f;
    int b = 0, total = 0;
    if (valid) { b = rptr[v]; total = rptr[v + 1] - b; }
    const int h0 = (total + 1) >> 1;            // wave0 takes ceil(total/2)
    const int mb = b + (wvh ? h0 : 0);
    const int mc = wvh ? (total - h0) : h0;

    float a0[8], a1[8], a2[8], a3[8];
#pragma unroll
    for (int c = 0; c < 8; ++c) { a0[c] = 0.f; a1[c] = 0.f; a2[c] = 0.f; a3[c] = 0.f; }
    if (wvh == 0 && valid) {
        const uint2 xv = *(const uint2*)(Xb + (size_t)v * HDIM + lane * 4);
        const float dv2 = dv * dv;
        a0[0] = dv2 * bf_lo(xv.x); a1[0] = dv2 * bf_hi(xv.x);
        a2[0] = dv2 * bf_lo(xv.y); a3[0] = dv2 * bf_hi(xv.y);
    }

    uint2 pv[8]; float pn[8];
#pragma unroll
    for (int c = 0; c < 8; ++c) {
        if (c < mc) {
            uint2 ed = edata[mb + c];
            pn[c] = dinv[ed.x] * __uint_as_float(ed.y) * dv;
            pv[c] = *(const uint2*)(Xb + (size_t)ed.x * HDIM + lane * 4);
        }
    }
    for (int base = 0; base < mc; base += 8) {
#pragma unroll
        for (int c = 0; c < 8; ++c) {
            if (base + c < mc) {
                uint2 cv = pv[c]; float cn = pn[c];
                int nx = base + 8 + c;
                if (nx < mc) {
                    uint2 ed = edata[mb + nx];
                    pn[c] = dinv[ed.x] * __uint_as_float(ed.y) * dv;
                    pv[c] = *(const uint2*)(Xb + (size_t)ed.x * HDIM + lane * 4);
                }
                a0[c] = fmaf(cn, bf_lo(cv.x), a0[c]);
                a1[c] = fmaf(cn, bf_hi(cv.x), a1[c]);
                a2[c] = fmaf(cn, bf_lo(cv.y), a2[c]);
                a3[c] = fmaf(cn, bf_hi(cv.y), a3[c]);
            }
        }
    }
    float r0 = ((a0[0] + a0[1]) + (a0[2] + a0[3])) + ((a0[4] + a0[5]) + (a0[6] + a0[7]));
    float r1 = ((a1[0] + a1[1]) + (a1[2] + a1[3])) + ((a1[4] + a1[5]) + (a1[6] + a1[7]));
    float r2 = ((a2[0] + a2[1]) + (a2[2] + a2[3])) + ((a2[4] + a2[5]) + (a2[6] + a2[7]));
    float r3 = ((a3[0] + a3[1]) + (a3[2] + a3[3])) + ((a3[4] + a3[5]) + (a3[6] + a3[7]));

    if (wvh == 1) part[pair][lane] = (float4){r0, r1, r2, r3};
    __syncthreads();
    if (wvh == 0 && valid) {
        const float4 p = part[pair][lane];
        uint2 o;
        o.x = cvt_pk_bf16(r0 + p.x, r1 + p.y);
        o.y = cvt_pk_bf16(r2 + p.z, r3 + p.w);
        *(uint2*)(out + (size_t)v * HDIM + lane * 4) = o;
    }
}

// ---------------- edge MLP: persistent, dbuf LDS, f32 staging (late cvt), PARTIAL W hoist ----------------
__global__ __launch_bounds__(256) void mlp_mfma_kernel(
    const float* __restrict__ A,            // [M][107] f32
    const ushort_t* __restrict__ Wp,        // [256][128] bf16, zero-padded k>=107
    const float* __restrict__ b1v, const float* __restrict__ g1v,
    const float* __restrict__ be1v, const float* __restrict__ W2,
    const float* __restrict__ b2s, float* __restrict__ out,
    int M, int ntiles) {
    __shared__ ushort_t As[2][64][136];
    __shared__ float ps1[64][4], ps2[64][4], pd[64][4];
    const int tid = threadIdx.x;
    const int l = tid & 63, wv = tid >> 6, g = l >> 4, c = l & 15;
    const float b2sc = b2s[0];
    const size_t tot = (size_t)M * KA;

    for (int z = tid; z < 2 * 64 * 16; z += 256) {
        int buf = z >> 10;
        int rem = z & 1023;
        As[buf][rem >> 4][112 + (rem & 15)] = 0;
    }

    const ushort_t* wb = Wp + (size_t)(wv * 64 + c) * KAP + g * 8;
    bf16x8 wreg[4][2];
#pragma unroll
    for (int ks = 0; ks < 4; ++ks)
#pragma unroll
        for (int nt = 0; nt < 2; ++nt)
            wreg[ks][nt] = *(const bf16x8*)(wb + nt * 16 * KAP + ks * 32);

    const int srow = tid >> 2, sj = tid & 3;
    float4 sreg[7];

    const int t0 = blockIdx.x;
    if (t0 < ntiles) {
        const size_t roff = (size_t)(t0 * 64 + srow) * KA + sj * 4;
#pragma unroll
        for (int i = 0; i < 7; ++i) sreg[i] = guarded_load4(A, roff + i * 16, tot);
#pragma unroll
        for (int i = 0; i < 7; ++i) {
            uint2 o;
            o.x = cvt_pk_bf16(sreg[i].x, sreg[i].y);
            o.y = cvt_pk_bf16(sreg[i].z, sreg[i].w);
            *(uint2*)&As[0][srow][sj * 4 + i * 16] = o;
        }
    }
    __syncthreads();

    int cur = 0;
    for (int t = t0; t < ntiles; t += gridDim.x) {
        const int tn = t + gridDim.x;
        const bool have_next = tn < ntiles;
        if (have_next) {
            const size_t roff = (size_t)(tn * 64 + srow) * KA + sj * 4;
#pragma unroll
            for (int i = 0; i < 7; ++i) sreg[i] = guarded_load4(A, roff + i * 16, tot);
        }

        f32x4 acc[4][4];
#pragma unroll
        for (int rt = 0; rt < 4; ++rt)
#pragma unroll
            for (int nt = 0; nt < 4; ++nt) acc[rt][nt] = (f32x4){0.f, 0.f, 0.f, 0.f};
        __builtin_amdgcn_s_setprio(1);
#pragma unroll
        for (int ks = 0; ks < 4; ++ks) {
            bf16x8 af[4];
#pragma unroll
            for (int rt = 0; rt < 4; ++rt)
                af[rt] = *(const bf16x8*)&As[cur][rt * 16 + c][ks * 32 + g * 8];
#pragma unroll
            for (int nt = 0; nt < 4; ++nt) {
                bf16x8 wfr = (nt < 2) ? wreg[ks][nt]
                                      : *(const bf16x8*)(wb + nt * 16 * KAP + ks * 32);
#pragma unroll
                for (int rt = 0; rt < 4; ++rt)
                    acc[rt][nt] = __builtin_amdgcn_mfma_f32_16x16x32_bf16(wfr, af[rt], acc[rt][nt], 0, 0, 0);
            }
        }
        __builtin_amdgcn_s_setprio(0);

        const int nb = wv * 64 + (g << 2);
        const int m0 = t * 64;
#pragma unroll
        for (int rt = 0; rt < 4; ++rt) {
            float s1 = 0.f, s2 = 0.f;
#pragma unroll
            for (int nt = 0; nt < 4; ++nt) {
                const float4 b4 = *(const float4*)(b1v + nb + nt * 16);
                f32x4 v = acc[rt][nt];
                v[0] += b4.x; v[1] += b4.y; v[2] += b4.z; v[3] += b4.w;
                acc[rt][nt] = v;
                s1 += v[0] + v[1] + v[2] + v[3];
                s2 += v[0] * v[0] + v[1] * v[1] + v[2] * v[2] + v[3] * v[3];
            }
            s1 += __shfl_xor(s1, 16); s1 += __shfl_xor(s1, 32);
            s2 += __shfl_xor(s2, 16); s2 += __shfl_xor(s2, 32);
            if (l < 16) { ps1[rt * 16 + c][wv] = s1; ps2[rt * 16 + c][wv] = s2; }
        }
        __syncthreads();   // barrier 1: ps published
#pragma unroll
        for (int rt = 0; rt < 4; ++rt) {
            float4 p1 = *(const float4*)ps1[rt * 16 + c];
            float4 p2 = *(const float4*)ps2[rt * 16 + c];
            float s1 = p1.x + p1.y + p1.z + p1.w;
            float s2 = p2.x + p2.y + p2.z + p2.w;
            float mu = s1 * (1.f / HDIM);
            float var = s2 * (1.f / HDIM) - mu * mu;
            float rs = rsqrtf(var + 1e-5f);
            float dacc = 0.f;
#pragma unroll
            for (int nt = 0; nt < 4; ++nt) {
                const float4 g4 = *(const float4*)(g1v + nb + nt * 16);
                const float4 e4 = *(const float4*)(be1v + nb + nt * 16);
                const float4 w4 = *(const float4*)(W2 + nb + nt * 16);
                f32x4 v = acc[rt][nt];
                float y0 = fmaxf((v[0] - mu) * rs * g4.x + e4.x, 0.f);
                float y1 = fmaxf((v[1] - mu) * rs * g4.y + e4.y, 0.f);
                float y2 = fmaxf((v[2] - mu) * rs * g4.z + e4.z, 0.f);
                float y3 = fmaxf((v[3] - mu) * rs * g4.w + e4.w, 0.f);
                dacc = fmaf(y0, w4.x, dacc); dacc = fmaf(y1, w4.y, dacc);
                dacc = fmaf(y2, w4.z, dacc); dacc = fmaf(y3, w4.w, dacc);
            }
            dacc += __shfl_xor(dacc, 16); dacc += __shfl_xor(dacc, 32);
            if (l < 16) pd[rt * 16 + c][wv] = dacc;
        }
        if (have_next) {
#pragma unroll
            for (int i = 0; i < 7; ++i) {
                uint2 o;
                o.x = cvt_pk_bf16(sreg[i].x, sreg[i].y);
                o.y = cvt_pk_bf16(sreg[i].z, sreg[i].w);
                *(uint2*)&As[cur ^ 1][srow][sj * 4 + i * 16] = o;
            }
        }
        __syncthreads();   // barrier 2: pd published + As[cur^1] complete
        if (tid < 64) {
            float4 p = *(const float4*)pd[tid];
            int gr = m0 + tid;
            if (gr < M) out[gr] = p.x + p.y + p.z + p.w + b2sc;
        }
        cur ^= 1;
    }
}

// ---------------- node GEMM: bf16 MFMA, C^T epilogue, fused LN(s), bf16 residuals ----------------
template <int MODE>
__global__ __launch_bounds__(256) void gemm_node_kernel(
    const ushort_t* __restrict__ A,
    const ushort_t* __restrict__ Wp,
    const float* __restrict__ bias,
    const ushort_t* __restrict__ res_bf,
    const ushort_t* __restrict__ orig_bf,
    const float* __restrict__ g1v, const float* __restrict__ b1v,
    const float* __restrict__ g2v, const float* __restrict__ b2v,
    float* __restrict__ out, ushort_t* __restrict__ out_bf, int M) {
    __shared__ ushort_t As[64][264];
    __shared__ float ps1[64][4], ps2[64][4], ps3[64][4], ps4[64][4];
    const int tid = threadIdx.x;
    const int m0 = blockIdx.x * 64;
    const int l = tid & 63, wv = tid >> 6, g = l >> 4, c = l & 15;

    {
        const int r = tid >> 2, j = tid & 3;
        const ushort_t* gsrc = A + (size_t)(m0 + r) * HDIM;
        const bool ok = (m0 + r) < M;
#pragma unroll
        for (int i = 0; i < 8; ++i) {
            const int ci = i * 4 + j;
            bf16x8 v = (bf16x8){0,0,0,0,0,0,0,0};
            if (ok) v = *(const bf16x8*)(gsrc + ci * 8);
            *(bf16x8*)&As[r][ci * 8] = v;
        }
    }
    __syncthreads();

    f32x4 acc[4][4];
#pragma unroll
    for (int rt = 0; rt < 4; ++rt)
#pragma unroll
        for (int nt = 0; nt < 4; ++nt) acc[rt][nt] = (f32x4){0.f, 0.f, 0.f, 0.f};

    const ushort_t* wb = Wp + (size_t)(wv * 64 + c) * HDIM + g * 8;
    __builtin_amdgcn_s_setprio(1);
#pragma unroll
    for (int ks = 0; ks < 8; ++ks) {
        bf16x8 af[4];
#pragma unroll
        for (int rt = 0; rt < 4; ++rt)
            af[rt] = *(const bf16x8*)&As[rt * 16 + c][ks * 32 + g * 8];
#pragma unroll
        for (int nt = 0; nt < 4; ++nt) {
            bf16x8 bfr = *(const bf16x8*)(wb + nt * 16 * HDIM + ks * 32);
#pragma unroll
            for (int rt = 0; rt < 4; ++rt)
                acc[rt][nt] = __builtin_amdgcn_mfma_f32_16x16x32_bf16(bfr, af[rt], acc[rt][nt], 0, 0, 0);
        }
    }
    __builtin_amdgcn_s_setprio(0);

    const int nb = wv * 64 + (g << 2);
#pragma unroll
    for (int rt = 0; rt < 4; ++rt) {
        const int m = m0 + rt * 16 + c;
        const bool vm = m < M;
        const ushort_t* rrow = res_bf + (size_t)m * HDIM + nb;
        float s1 = 0.f, s2 = 0.f;
#pragma unroll
        for (int nt = 0; nt < 4; ++nt) {
            const float4 b4 = *(const float4*)(bias + nb + nt * 16);
            float4 r4 = {0.f, 0.f, 0.f, 0.f};
            if (vm) {
                uint2 rb = *(const uint2*)(rrow + nt * 16);
                r4.x = bf_lo(rb.x); r4.y = bf_hi(rb.x);
                r4.z = bf_lo(rb.y); r4.w = bf_hi(rb.y);
            }
            f32x4 v = acc[rt][nt];
            v[0] += b4.x + r4.x; v[1] += b4.y + r4.y;
            v[2] += b4.z + r4.z; v[3] += b4.w + r4.w;
            acc[rt][nt] = v;
            s1 += v[0] + v[1] + v[2] + v[3];
            s2 += v[0] * v[0] + v[1] * v[1] + v[2] * v[2] + v[3] * v[3];
        }
        s1 += __shfl_xor(s1, 16); s1 += __shfl_xor(s1, 32);
        s2 += __shfl_xor(s2, 16); s2 += __shfl_xor(s2, 32);
        if (l < 16) { ps1[rt * 16 + c][wv] = s1; ps2[rt * 16 + c][wv] = s2; }
    }
    __syncthreads();
#pragma unroll
    for (int rt = 0; rt < 4; ++rt) {
        const int m = m0 + rt * 16 + c;
        const bool vm = m < M;
        float4 p1 = *(const float4*)ps1[rt * 16 + c];
        float4 p2 = *(const float4*)ps2[rt * 16 + c];
        float s1 = p1.x + p1.y + p1.z + p1.w;
        float s2 = p2.x + p2.y + p2.z + p2.w;
        float mu = s1 * (1.f / HDIM);
        float var = s2 * (1.f / HDIM) - mu * mu;
        float rs = rsqrtf(var + 1e-5f);
        if constexpr (MODE == 0) {
            ushort_t* obrow = out_bf + (size_t)m * HDIM + nb;
#pragma unroll
            for (int nt = 0; nt < 4; ++nt) {
                const float4 g4 = *(const float4*)(g1v + nb + nt * 16);
                const float4 e4 = *(const float4*)(b1v + nb + nt * 16);
                f32x4 v = acc[rt][nt];
                float o0 = fmaxf((v[0] - mu) * rs * g4.x + e4.x, 0.f);
                float o1 = fmaxf((v[1] - mu) * rs * g4.y + e4.y, 0.f);
                float o2 = fmaxf((v[2] - mu) * rs * g4.z + e4.z, 0.f);
                float o3 = fmaxf((v[3] - mu) * rs * g4.w + e4.w, 0.f);
                if (vm) {
                    uint2 ob;
                    ob.x = cvt_pk_bf16(o0, o1);
                    ob.y = cvt_pk_bf16(o2, o3);
                    *(uint2*)(obrow + nt * 16) = ob;
                }
            }
        } else {
            const ushort_t* grow = orig_bf + (size_t)m * HDIM + nb;
            float t1 = 0.f, t2 = 0.f;
#pragma unroll
            for (int nt = 0; nt < 4; ++nt) {
                const float4 g4 = *(const float4*)(g1v + nb + nt * 16);
                const float4 e4 = *(const float4*)(b1v + nb + nt * 16);
                float4 o4 = {0.f, 0.f, 0.f, 0.f};
                if (vm) {
                    uint2 gb = *(const uint2*)(grow + nt * 16);
                    o4.x = bf_lo(gb.x); o4.y = bf_hi(gb.x);
                    o4.z = bf_lo(gb.y); o4.w = bf_hi(gb.y);
                }
                f32x4 v = acc[rt][nt];
                f32x4 u;
                u[0] = fmaxf((v[0] - mu) * rs * g4.x + e4.x, 0.f) + o4.x;
                u[1] = fmaxf((v[1] - mu) * rs * g4.y + e4.y, 0.f) + o4.y;
                u[2] = fmaxf((v[2] - mu) * rs * g4.z + e4.z, 0.f) + o4.z;
                u[3] = fmaxf((v[3] - mu) * rs * g4.w + e4.w, 0.f) + o4.w;
                acc[rt][nt] = u;
                t1 += u[0] + u[1] + u[2] + u[3];
                t2 += u[0] * u[0] + u[1] * u[1] + u[2] * u[2] + u[3] * u[3];
            }
            t1 += __shfl_xor(t1, 16); t1 += __shfl_xor(t1, 32);
            t2 += __shfl_xor(t2, 16); t2 += __shfl_xor(t2, 32);
            if (l < 16) { ps3[rt * 16 + c][wv] = t1; ps4[rt * 16 + c][wv] = t2; }
        }
    }
    if constexpr (MODE == 1) {
        __syncthreads();
#pragma unroll
        for (int rt = 0; rt < 4; ++rt) {
            const int m = m0 + rt * 16 + c;
            const bool vm = m < M;
            float4 p1 = *(const float4*)ps3[rt * 16 + c];
            float4 p2 = *(const float4*)ps4[rt * 16 + c];
            float s1 = p1.x + p1.y + p1.z + p1.w;
            float s2 = p2.x + p2.y + p2.z + p2.w;
            float mu2 = s1 * (1.f / HDIM);
            float var2 = s2 * (1.f / HDIM) - mu2 * mu2;
            float rs2 = rsqrtf(var2 + 1e-5f);
            float* orow = out + (size_t)m * HDIM + nb;
#pragma unroll
            for (int nt = 0; nt < 4; ++nt) {
                const float4 g4 = *(const float4*)(g2v + nb + nt * 16);
                const float4 e4 = *(const float4*)(b2v + nb + nt * 16);
                f32x4 u = acc[rt][nt];
                float4 o;
                o.x = (u[0] - mu2) * rs2 * g4.x + e4.x;
                o.y = (u[1] - mu2) * rs2 * g4.y + e4.y;
                o.z = (u[2] - mu2) * rs2 * g4.z + e4.z;
                o.w = (u[3] - mu2) * rs2 * g4.w + e4.w;
                if (vm) *(float4*)(orow + nt * 16) = o;
            }
        }
    }
}

// ---------------- launch ----------------

extern "C" void kernel_launch(void* const* d_in, const int* in_sizes, int n_in,
                              void* d_out, int out_size, void* d_ws, size_t ws_size,
                              hipStream_t stream) {
    const float* x    = (const float*)d_in[0];
    const int*   eib  = (const int*)d_in[1];
    const float* eab  = (const float*)d_in[2];
    const int*   eit  = (const int*)d_in[3];
    const float* eat  = (const float*)d_in[4];
    const float* Wb   = (const float*)d_in[5];
    const float* bb   = (const float*)d_in[6];
    const float* Wt   = (const float*)d_in[7];
    const float* bt   = (const float*)d_in[8];
    const float* W1   = (const float*)d_in[9];
    const float* b1   = (const float*)d_in[10];
    const float* g1   = (const float*)d_in[11];
    const float* be1  = (const float*)d_in[12];
    const float* W2   = (const float*)d_in[13];
    const float* b2   = (const float*)d_in[14];
    const float* gs   = (const float*)d_in[15];
    const float* bs   = (const float*)d_in[16];
    const float* gt   = (const float*)d_in[17];
    const float* btn  = (const float*)d_in[18];

    const int Nn = in_sizes[0] / HDIM;     // 50000
    const int Ne = in_sizes[2];            // 800000

    const int* src_b = eib;  const int* dst_b = eib + Ne;
    const int* src_t = eit;  const int* dst_t = eit + Ne;

    char* w = (char*)d_ws;
    ushort_t* aggb = (ushort_t*)w; w += (size_t)Nn * HDIM * 2;
    ushort_t* xb   = (ushort_t*)w; w += (size_t)Nn * HDIM * 2;
    ushort_t* x1b  = (ushort_t*)w; w += (size_t)Nn * HDIM * 2;
    float*    wtmp = (float*)w;    w += (size_t)Ne * 4;
    float*    dinv = (float*)w;    w += (size_t)Nn * 4;
    int*      cnt  = (int*)w;      w += (size_t)Nn * 4;
    int*      rptr = (int*)w;      w += (size_t)(Nn + 4) * 4;
    int*      cur  = (int*)w;      w += (size_t)Nn * 4;
    uint2*    edata = (uint2*)w;   w += (size_t)Ne * 8;
    int*      bsum = (int*)w;      w += (size_t)256 * 4;
    ushort_t* W1p  = (ushort_t*)w; w += (size_t)256 * KAP * 2;
    ushort_t* Wbp  = (ushort_t*)w; w += (size_t)256 * 256 * 2;
    ushort_t* Wtp  = (ushort_t*)w; w += (size_t)256 * 256 * 2;

    float* out = (float*)d_out;
    dim3 b256(256);
    dim3 gN((Nn + 255) / 256), gE((Ne + 255) / 256);
    const int nbScan = (Nn + 255) / 256;
    dim3 gAgg((Nn + 1) / 2);
    dim3 gGemmN((Nn + 63) / 64);
    const int ntiles = (Ne + 63) / 64;
    dim3 gMlp(512);
    const int n4 = Nn * HDIM / 4;
    dim3 gCvt((n4 + 255) / 256);
    const int nPrep = 256 * KAP + 2 * 256 * 256;

    // ---- weight prep (bf16, fused) + x mirror ----
    prep_all_w_kernel<<<dim3((nPrep + 255) / 256), b256, 0, stream>>>(W1, W1p, Wb, Wbp, Wt, Wtp);
    f32_to_bf16_kernel<<<gCvt, b256, 0, stream>>>(x, xb, n4);

    // ---- stage A: BOLD GCN ----
    hipMemsetAsync(cnt, 0, (size_t)Nn * 4, stream);
    hist_cnt_kernel<<<gE, b256, 0, stream>>>(dst_b, cnt, Ne);
    scan_a_kernel<<<dim3(nbScan), b256, 0, stream>>>(cnt, bsum, Nn);
    scan_b_kernel<<<dim3(1), b256, 0, stream>>>(bsum, nbScan);
    scan_c_kernel<<<dim3(nbScan), b256, 0, stream>>>(cnt, bsum, rptr, cur, Nn);
    fill_kernel<<<gE, b256, 0, stream>>>(src_b, dst_b, eab, cur, edata, Ne);
    deg_kernel<<<gN, b256, 0, stream>>>(edata, rptr, dinv, Nn);
    agg_kernel<<<gAgg, b256, 0, stream>>>(xb, rptr, edata, dinv, aggb, Nn);
    gemm_node_kernel<0><<<gGemmN, b256, 0, stream>>>(
        aggb, Wbp, bb, xb, nullptr, gs, bs, nullptr, nullptr, nullptr, x1b, Nn);

    // ---- temporal edge-weight MLP (persistent, dbuf, partial hoist) ----
    mlp_mfma_kernel<<<gMlp, b256, 0, stream>>>(
        eat, W1p, b1, g1, be1, W2, b2, wtmp, Ne, ntiles);

    // ---- stage B: temporal GCN + final LN ----
    hipMemsetAsync(cnt, 0, (size_t)Nn * 4, stream);
    hist_cnt_kernel<<<gE, b256, 0, stream>>>(dst_t, cnt, Ne);
    scan_a_kernel<<<dim3(nbScan), b256, 0, stream>>>(cnt, bsum, Nn);
    scan_b_kernel<<<dim3(1), b256, 0, stream>>>(bsum, nbScan);
    scan_c_kernel<<<dim3(nbScan), b256, 0, stream>>>(cnt, bsum, rptr, cur, Nn);
    fill_kernel<<<gE, b256, 0, stream>>>(src_t, dst_t, wtmp, cur, edata, Ne);
    deg_kernel<<<gN, b256, 0, stream>>>(edata, rptr, dinv, Nn);
    agg_kernel<<<gAgg, b256, 0, stream>>>(x1b, rptr, edata, dinv, aggb, Nn);
    gemm_node_kernel<1><<<gGemmN, b256, 0, stream>>>(
        aggb, Wtp, bt, x1b, xb, gt, btn, gs, bs, out, nullptr, Nn);
}